// Round 1
// baseline (692.768 us; speedup 1.0000x reference)
//
#include <hip/hip_runtime.h>
#include <hip/hip_bf16.h>
#include <stdint.h>

#define Bb 8
#define Nn 1500
#define Ee 3000
#define Hh 256
#define NHOPS 3
#define CAP 32
#define Mrows (Bb*Nn)      // 12000
#define BE (Bb*Ee)         // 24000
#define BN (Bb*Nn)         // 12000

typedef __bf16 bf16x8 __attribute__((ext_vector_type(8)));
typedef float f32x4 __attribute__((ext_vector_type(4)));

__device__ __forceinline__ float sigmoidf_(float x){ return 1.f/(1.f+__expf(-x)); }

__device__ __forceinline__ unsigned short f2b(float f){
  union { float f; unsigned int u; } x; x.f = f;
  unsigned int r = (x.u + 0x7fffu + ((x.u >> 16) & 1u)) >> 16;
  return (unsigned short)r;
}
__device__ __forceinline__ float b2f(unsigned short u){
  union { unsigned int u; float f; } x; x.u = ((unsigned int)u) << 16;
  return x.f;
}

// ---------- preprocess: row scan (ballot compaction) + atomic column scatter ----------
__global__ void rowscan_kernel(const float* __restrict__ mat, int R, int C,
                               int* __restrict__ rowIdx, int* __restrict__ rowCnt,
                               int* __restrict__ colIdx, int* __restrict__ colCnt) {
  int g = blockIdx.x * 4 + (threadIdx.x >> 6);
  if (g >= Bb * R) return;
  int b = g / R;
  int lane = threadIdx.x & 63;
  const float* base = mat + (size_t)g * C;
  int cnt = 0;
  for (int c0 = 0; c0 < C; c0 += 64) {
    int c = c0 + lane;
    float v = (c < C) ? base[c] : 0.f;
    unsigned long long mask = __ballot(v != 0.f);
    if (v != 0.f) {
      int pos = cnt + __popcll(mask & ((1ull << lane) - 1ull));
      if (pos < CAP) rowIdx[(size_t)g * CAP + pos] = c;
      int slot = atomicAdd(&colCnt[b * C + c], 1);
      if (slot < CAP) colIdx[(size_t)(b * C + c) * CAP + slot] = g - b * R;
    }
    cnt += __popcll(mask);
  }
  if (lane == 0) rowCnt[g] = cnt;
}

__global__ void sort_kernel(int* __restrict__ idx, const int* __restrict__ cnt, int nLists) {
  int i = blockIdx.x * 256 + threadIdx.x;
  if (i >= nLists) return;
  int c = cnt[i]; if (c > CAP) c = CAP;
  int* pp = idx + (size_t)i * CAP;
  int v[CAP];
  for (int j = 0; j < c; ++j) v[j] = pp[j];
  for (int j = 1; j < c; ++j) { int key = v[j]; int k = j - 1;
    while (k >= 0 && v[k] > key) { v[k+1] = v[k]; --k; } v[k+1] = key; }
  for (int j = 0; j < c; ++j) pp[j] = v[j];
}

// ---------- weight transposes to bf16 (W^T layout [Nout][K]) ----------
__global__ void wtrans_kernel(const float* __restrict__ W, unsigned short* __restrict__ WT,
                              int K, int Ncol) {
  int t = blockIdx.x * 256 + threadIdx.x;
  if (t >= K * Ncol) return;
  int n = t / K, k = t % K;
  WT[t] = f2b(W[k * Ncol + n]);
}
__global__ void wzr_kernel(const float* __restrict__ Wz, const float* __restrict__ Wr,
                           unsigned short* __restrict__ WT) {
  int t = blockIdx.x * 256 + threadIdx.x;
  if (t >= 512 * 512) return;
  int j = t / 512, k = t % 512;
  float v = (j < 256) ? Wz[k * 256 + j] : Wr[k * 256 + (j - 256)];
  WT[t] = f2b(v);
}

// ---------- per-hop: edge embedding (both directions) ----------
__global__ void edge_kernel(const float* __restrict__ edge_vec, const float* __restrict__ ns,
                            const int* __restrict__ Aidx, const int* __restrict__ Acnt,
                            const int* __restrict__ Cidx, const int* __restrict__ Ccnt,
                            float* __restrict__ eb, float* __restrict__ ef) {
  int be = blockIdx.x;            // b*E + e
  int b = be / Ee;
  int h = threadIdx.x;
  __shared__ int lA[CAP], lC[CAP];
  __shared__ int rA, rC;
  if (threadIdx.x == 0) { rA = Acnt[be]; rC = Ccnt[be]; }
  if (threadIdx.x < CAP) {
    lA[threadIdx.x] = Aidx[(size_t)be * CAP + threadIdx.x];
    lC[threadIdx.x] = Cidx[(size_t)be * CAP + threadIdx.x];
  }
  __syncthreads();
  int cA = min(rA, CAP), cC = min(rC, CAP);
  float ev = edge_vec[(size_t)be * Hh + h];
  float sA = ev, sC = ev;
  for (int i = 0; i < cA; ++i) sA += ns[((size_t)b * Nn + lA[i]) * Hh + h];
  for (int i = 0; i < cC; ++i) sC += ns[((size_t)b * Nn + lC[i]) * Hh + h];
  eb[(size_t)be * Hh + h] = sA;
  ef[(size_t)be * Hh + h] = sC;
}

// ---------- per-hop: node aggregation + build GEMM inputs ----------
__global__ void node_kernel(const float* __restrict__ ns,
                            const float* __restrict__ eb, const float* __restrict__ ef,
                            const int* __restrict__ Bidx, const int* __restrict__ Bcnt,
                            const int* __restrict__ Didx, const int* __restrict__ Dcnt,
                            unsigned short* __restrict__ Xfz, unsigned short* __restrict__ Xzr) {
  int bn = blockIdx.x;            // b*N + n == m
  int b = bn / Nn;
  int h = threadIdx.x;
  __shared__ int lB[CAP], lD[CAP];
  __shared__ int rB, rD;
  if (threadIdx.x == 0) { rB = Bcnt[bn]; rD = Dcnt[bn]; }
  if (threadIdx.x < CAP) {
    lB[threadIdx.x] = Bidx[(size_t)bn * CAP + threadIdx.x];
    lD[threadIdx.x] = Didx[(size_t)bn * CAP + threadIdx.x];
  }
  __syncthreads();
  int cB = min(rB, CAP), cD = min(rD, CAP);
  float h0 = ns[(size_t)bn * Hh + h];
  float sb = h0, sf = h0;
  for (int i = 0; i < cB; ++i) sb += eb[((size_t)b * Ee + lB[i]) * Hh + h];
  for (int i = 0; i < cD; ++i) sf += ef[((size_t)b * Ee + lD[i]) * Hh + h];
  sb /= (1.f + (float)rB);
  sf /= (1.f + (float)rD);
  size_t m = bn;
  Xfz[m * 1024 + h]       = f2b(sf);
  Xfz[m * 1024 + 256 + h] = f2b(sb);
  Xfz[m * 1024 + 512 + h] = f2b(sf * sb);
  Xfz[m * 1024 + 768 + h] = f2b(sf - sb);
  Xzr[m * 512 + h] = f2b(h0);
}

// ---------- bf16 MFMA GEMM with fused epilogues ----------
#define EPI_NONE 0
#define EPI_FZ   1
#define EPI_ZR   2
#define EPI_GRU  3

template<int EPI>
__global__ __launch_bounds__(256) void gemm_kernel(
    const unsigned short* __restrict__ A, const unsigned short* __restrict__ WT,
    int M, int Nout, int K,
    float* __restrict__ outf, const float* __restrict__ bfz,
    unsigned short* __restrict__ Xzr, float* __restrict__ zbuf,
    unsigned short* __restrict__ Xt, float* __restrict__ ns)
{
  __shared__ unsigned short As[64][72];
  __shared__ unsigned short Bs[64][72];
  int m0 = blockIdx.x * 64, n0 = blockIdx.y * 64;
  int tid = threadIdx.x;
  int lane = tid & 63, wid = tid >> 6;
  int wm = wid >> 1, wn = wid & 1;
  f32x4 acc[2][2] = {};
  for (int k0 = 0; k0 < K; k0 += 64) {
    #pragma unroll
    for (int s = 0; s < 2; ++s) {
      int chunk = tid + s * 256;     // 0..511
      int row = chunk >> 3;
      int co = (chunk & 7) * 8;
      int gm = m0 + row;
      uint4 va = make_uint4(0, 0, 0, 0);
      if (gm < M) va = *(const uint4*)(A + (size_t)gm * K + k0 + co);
      *(uint4*)(&As[row][co]) = va;
      uint4 vb = *(const uint4*)(WT + (size_t)(n0 + row) * K + k0 + co);
      *(uint4*)(&Bs[row][co]) = vb;
    }
    __syncthreads();
    int ko = (lane >> 4) * 8;
    int ra = wm * 32 + (lane & 15);
    int rb = wn * 32 + (lane & 15);
    #pragma unroll
    for (int kk = 0; kk < 64; kk += 32) {
      bf16x8 a0 = *(const bf16x8*)(&As[ra][kk + ko]);
      bf16x8 a1 = *(const bf16x8*)(&As[ra + 16][kk + ko]);
      bf16x8 b0 = *(const bf16x8*)(&Bs[rb][kk + ko]);
      bf16x8 b1 = *(const bf16x8*)(&Bs[rb + 16][kk + ko]);
      acc[0][0] = __builtin_amdgcn_mfma_f32_16x16x32_bf16(a0, b0, acc[0][0], 0, 0, 0);
      acc[0][1] = __builtin_amdgcn_mfma_f32_16x16x32_bf16(a0, b1, acc[0][1], 0, 0, 0);
      acc[1][0] = __builtin_amdgcn_mfma_f32_16x16x32_bf16(a1, b0, acc[1][0], 0, 0, 0);
      acc[1][1] = __builtin_amdgcn_mfma_f32_16x16x32_bf16(a1, b1, acc[1][1], 0, 0, 0);
    }
    __syncthreads();
  }
  #pragma unroll
  for (int mi = 0; mi < 2; ++mi)
  #pragma unroll
  for (int ni = 0; ni < 2; ++ni)
  #pragma unroll
  for (int j = 0; j < 4; ++j) {
    int m = m0 + wm * 32 + mi * 16 + (lane >> 4) * 4 + j;
    int c = n0 + wn * 32 + ni * 16 + (lane & 15);
    if (m >= M) continue;
    float v = acc[mi][ni][j];
    if (EPI == EPI_NONE) {
      outf[(size_t)m * 256 + c] = v;
    } else if (EPI == EPI_FZ) {
      float z = sigmoidf_(v + bfz[c]);
      float fw = b2f(A[(size_t)m * K + c]);
      float bw = b2f(A[(size_t)m * K + 256 + c]);
      Xzr[(size_t)m * 512 + 256 + c] = f2b((1.f - z) * fw + z * bw);
    } else if (EPI == EPI_ZR) {
      float s = sigmoidf_(v);
      if (c < 256) {
        zbuf[(size_t)m * 256 + c] = s;
        Xt[(size_t)m * 512 + 256 + c] = A[(size_t)m * 512 + 256 + c];  // copy bf16(agg)
      } else {
        int cz = c - 256;
        Xt[(size_t)m * 512 + cz] = f2b(s * ns[(size_t)m * 256 + cz]);  // r*h
      }
    } else { // EPI_GRU
      float t = tanhf(v);
      float zz = zbuf[(size_t)m * 256 + c];
      float h = ns[(size_t)m * 256 + c];
      ns[(size_t)m * 256 + c] = (1.f - zz) * h + zz * t;
    }
  }
}

// ---------- output ----------
__global__ void transpose_out_kernel(const float* __restrict__ ns, float* __restrict__ out,
                                     unsigned short* __restrict__ nsb) {
  int bn = blockIdx.x;             // b*N + n
  int b = bn / Nn, n = bn % Nn;
  int h = threadIdx.x;
  float v = ns[(size_t)bn * Hh + h];
  out[((size_t)n * Bb + b) * Hh + h] = v;
  nsb[(size_t)bn * Hh + h] = f2b(v);
}

__global__ void maxpart_kernel(const float* __restrict__ tmp, float* __restrict__ part) {
  int bc = blockIdx.x;             // b*12 + chunk (125 rows each)
  int b = bc / 12, ch = bc % 12;
  int h = threadIdx.x;
  float m = -1e30f;
  int nbase = ch * 125;
  for (int i = 0; i < 125; ++i)
    m = fmaxf(m, tmp[((size_t)b * Nn + nbase + i) * Hh + h]);
  part[(size_t)bc * Hh + h] = m;
}
__global__ void maxfin_kernel(const float* __restrict__ part, float* __restrict__ out) {
  int t = blockIdx.x * 256 + threadIdx.x;   // b*256 + h
  if (t >= Bb * Hh) return;
  int b = t / Hh, h = t % Hh;
  float m = -1e30f;
  for (int c = 0; c < 12; ++c) m = fmaxf(m, part[((size_t)b * 12 + c) * Hh + h]);
  out[(size_t)Nn * Bb * Hh + t] = m;
}

extern "C" void kernel_launch(void* const* d_in, const int* in_sizes, int n_in,
                              void* d_out, int out_size, void* d_ws, size_t ws_size,
                              hipStream_t stream) {
  const float* in_ns   = (const float*)d_in[0];
  const float* in_ev   = (const float*)d_in[1];
  const float* in_n2e  = (const float*)d_in[2];   // (B,E,N)
  const float* in_e2n  = (const float*)d_in[3];   // (B,N,E)
  const float* in_wmax = (const float*)d_in[4];
  const float* in_wfz  = (const float*)d_in[5];
  const float* in_bfz  = (const float*)d_in[6];
  const float* in_wz   = (const float*)d_in[7];
  const float* in_wr   = (const float*)d_in[8];
  const float* in_wt   = (const float*)d_in[9];
  float* out = (float*)d_out;

  char* base = (char*)d_ws;
  size_t off = 0;
  auto alloc = [&](size_t bytes) -> void* {
    void* r = base + off;
    off = (off + bytes + 255) & ~(size_t)255;
    return r;
  };
  int* cntA = (int*)alloc(BE * 4);
  int* Aidx = (int*)alloc((size_t)BE * CAP * 4);
  int* cntB = (int*)alloc(BN * 4);
  int* Bidx = (int*)alloc((size_t)BN * CAP * 4);
  int* cntC = (int*)alloc(BE * 4);
  int* Cidx = (int*)alloc((size_t)BE * CAP * 4);
  int* cntD = (int*)alloc(BN * 4);
  int* Didx = (int*)alloc((size_t)BN * CAP * 4);
  float* ns   = (float*)alloc((size_t)Mrows * Hh * 4);
  float* eb   = (float*)alloc((size_t)BE * Hh * 4);   // also reused as GEMM4 out
  float* ef   = (float*)alloc((size_t)BE * Hh * 4);
  unsigned short* Xfz = (unsigned short*)alloc((size_t)Mrows * 1024 * 2);
  unsigned short* Xzr = (unsigned short*)alloc((size_t)Mrows * 512 * 2);
  unsigned short* Xt  = (unsigned short*)alloc((size_t)Mrows * 512 * 2);
  float* zbuf = (float*)alloc((size_t)Mrows * 256 * 4);
  unsigned short* nsb = (unsigned short*)alloc((size_t)Mrows * 256 * 2);
  float* part = (float*)alloc((size_t)Bb * 12 * Hh * 4);
  unsigned short* WfzT  = (unsigned short*)alloc(256 * 1024 * 2);
  unsigned short* WzrT  = (unsigned short*)alloc(512 * 512 * 2);
  unsigned short* WtT   = (unsigned short*)alloc(256 * 512 * 2);
  unsigned short* WmaxT = (unsigned short*)alloc(256 * 256 * 2);
  (void)ws_size; (void)in_sizes; (void)n_in; (void)out_size;

  hipMemsetAsync(cntC, 0, BE * 4, stream);
  hipMemsetAsync(cntD, 0, BN * 4, stream);
  hipMemcpyAsync(ns, in_ns, (size_t)Mrows * Hh * 4, hipMemcpyDeviceToDevice, stream);

  wtrans_kernel<<<(1024 * 256 + 255) / 256, 256, 0, stream>>>(in_wfz, WfzT, 1024, 256);
  wzr_kernel<<<(512 * 512 + 255) / 256, 256, 0, stream>>>(in_wz, in_wr, WzrT);
  wtrans_kernel<<<(512 * 256 + 255) / 256, 256, 0, stream>>>(in_wt, WtT, 512, 256);
  wtrans_kernel<<<(256 * 256 + 255) / 256, 256, 0, stream>>>(in_wmax, WmaxT, 256, 256);

  // n2e: rows = edges (list A), column scatter -> D (node->edges), colCnt = cntD
  rowscan_kernel<<<(Bb * Ee) / 4, 256, 0, stream>>>(in_n2e, Ee, Nn, Aidx, cntA, Didx, cntD);
  // e2n: rows = nodes (list B), column scatter -> C (edge->nodes), colCnt = cntC
  rowscan_kernel<<<(Bb * Nn) / 4, 256, 0, stream>>>(in_e2n, Nn, Ee, Bidx, cntB, Cidx, cntC);
  sort_kernel<<<(BE + 255) / 256, 256, 0, stream>>>(Cidx, cntC, BE);
  sort_kernel<<<(BN + 255) / 256, 256, 0, stream>>>(Didx, cntD, BN);

  dim3 g1(188, 4), g2(188, 8);
  for (int hop = 0; hop < NHOPS; ++hop) {
    edge_kernel<<<BE, 256, 0, stream>>>(in_ev, ns, Aidx, cntA, Cidx, cntC, eb, ef);
    node_kernel<<<BN, 256, 0, stream>>>(ns, eb, ef, Bidx, cntB, Didx, cntD, Xfz, Xzr);
    gemm_kernel<EPI_FZ><<<g1, 256, 0, stream>>>(Xfz, WfzT, Mrows, 256, 1024,
        nullptr, in_bfz, Xzr, nullptr, nullptr, nullptr);
    gemm_kernel<EPI_ZR><<<g2, 256, 0, stream>>>(Xzr, WzrT, Mrows, 512, 512,
        nullptr, nullptr, nullptr, zbuf, Xt, ns);
    gemm_kernel<EPI_GRU><<<g1, 256, 0, stream>>>(Xt, WtT, Mrows, 256, 512,
        nullptr, nullptr, nullptr, zbuf, nullptr, ns);
  }

  transpose_out_kernel<<<BN, 256, 0, stream>>>(ns, out, nsb);
  gemm_kernel<EPI_NONE><<<g1, 256, 0, stream>>>(nsb, WmaxT, Mrows, 256, 256,
      eb, nullptr, nullptr, nullptr, nullptr, nullptr);
  maxpart_kernel<<<Bb * 12, 256, 0, stream>>>(eb, part);
  maxfin_kernel<<<(Bb * Hh + 255) / 256, 256, 0, stream>>>(part, out);
}

// Round 2
// 524.135 us; speedup vs baseline: 1.3217x; 1.3217x over previous
//
#include <hip/hip_runtime.h>
#include <hip/hip_bf16.h>
#include <stdint.h>

#define Bb 8
#define Nn 1500
#define Ee 3000
#define Hh 256
#define NHOPS 3
#define CAP 32
#define Mrows (Bb*Nn)      // 12000
#define BE (Bb*Ee)         // 24000
#define BN (Bb*Nn)         // 12000

typedef __bf16 bf16x8 __attribute__((ext_vector_type(8)));
typedef float f32x4 __attribute__((ext_vector_type(4)));

__device__ __forceinline__ float sigmoidf_(float x){ return 1.f/(1.f+__expf(-x)); }

__device__ __forceinline__ unsigned short f2b(float f){
  union { float f; unsigned int u; } x; x.f = f;
  unsigned int r = (x.u + 0x7fffu + ((x.u >> 16) & 1u)) >> 16;
  return (unsigned short)r;
}
__device__ __forceinline__ float b2f(unsigned short u){
  union { unsigned int u; float f; } x; x.u = ((unsigned int)u) << 16;
  return x.f;
}
__device__ __forceinline__ ushort4 pack4(float4 v){
  return make_ushort4(f2b(v.x), f2b(v.y), f2b(v.z), f2b(v.w));
}
__device__ __forceinline__ float4 unpack4(ushort4 u){
  return make_float4(b2f(u.x), b2f(u.y), b2f(u.z), b2f(u.w));
}

// ---------- preprocess: float4 row scan (4-ballot compaction) + atomic column scatter ----------
__global__ void rowscan_kernel(const float* __restrict__ mat, int R, int C,
                               int* __restrict__ rowIdx, int* __restrict__ rowCnt,
                               int* __restrict__ colIdx, int* __restrict__ colCnt) {
  int w = __builtin_amdgcn_readfirstlane((int)(threadIdx.x >> 6));
  int g = blockIdx.x * 4 + w;
  if (g >= Bb * R) return;
  int b = g / R;
  int lane = threadIdx.x & 63;
  const float4* base = (const float4*)(mat + (size_t)g * C);
  int nq = C >> 2;                 // float4 per row (C % 4 == 0)
  int cnt = 0;
  for (int q0 = 0; q0 < nq; q0 += 64) {
    int q = q0 + lane;
    float4 v = make_float4(0.f, 0.f, 0.f, 0.f);
    if (q < nq) v = base[q];
    unsigned long long m0 = __ballot(v.x != 0.f);
    unsigned long long m1 = __ballot(v.y != 0.f);
    unsigned long long m2 = __ballot(v.z != 0.f);
    unsigned long long m3 = __ballot(v.w != 0.f);
    unsigned long long below = (1ull << lane) - 1ull;
    int myc = cnt + __popcll(m0 & below) + __popcll(m1 & below)
                  + __popcll(m2 & below) + __popcll(m3 & below);
    int c = q * 4;
    #pragma unroll
    for (int j = 0; j < 4; ++j) {
      float vv = (j == 0) ? v.x : (j == 1) ? v.y : (j == 2) ? v.z : v.w;
      if (vv != 0.f) {
        if (myc < CAP) rowIdx[(size_t)g * CAP + myc] = c + j;
        int slot = atomicAdd(&colCnt[b * C + c + j], 1);
        if (slot < CAP) colIdx[(size_t)(b * C + c + j) * CAP + slot] = g - b * R;
        ++myc;
      }
    }
    cnt += __popcll(m0) + __popcll(m1) + __popcll(m2) + __popcll(m3);
  }
  if (lane == 0) rowCnt[g] = cnt;
}

__global__ void sort_kernel(int* __restrict__ idx, const int* __restrict__ cnt, int nLists) {
  int i = blockIdx.x * 256 + threadIdx.x;
  if (i >= nLists) return;
  int c = cnt[i]; if (c > CAP) c = CAP;
  int* pp = idx + (size_t)i * CAP;
  int v[CAP];
  for (int j = 0; j < c; ++j) v[j] = pp[j];
  for (int j = 1; j < c; ++j) { int key = v[j]; int k = j - 1;
    while (k >= 0 && v[k] > key) { v[k+1] = v[k]; --k; } v[k+1] = key; }
  for (int j = 0; j < c; ++j) pp[j] = v[j];
}

// ---------- weight transposes to bf16 (W^T layout [Nout][K]) ----------
__global__ void wtrans_kernel(const float* __restrict__ W, unsigned short* __restrict__ WT,
                              int K, int Ncol) {
  int t = blockIdx.x * 256 + threadIdx.x;
  if (t >= K * Ncol) return;
  int n = t / K, k = t % K;
  WT[t] = f2b(W[k * Ncol + n]);
}
__global__ void wzr_kernel(const float* __restrict__ Wz, const float* __restrict__ Wr,
                           unsigned short* __restrict__ WT) {
  int t = blockIdx.x * 256 + threadIdx.x;
  if (t >= 512 * 512) return;
  int j = t / 512, k = t % 512;
  float v = (j < 256) ? Wz[k * 256 + j] : Wr[k * 256 + (j - 256)];
  WT[t] = f2b(v);
}

// ---------- per-hop: edge embedding (both directions), float4, 4 edges/block ----------
__global__ void edge_kernel(const float4* __restrict__ ev4, const float4* __restrict__ ns4,
                            const int* __restrict__ Aidx, const int* __restrict__ Acnt,
                            const int* __restrict__ Cidx, const int* __restrict__ Ccnt,
                            ushort4* __restrict__ eb4, ushort4* __restrict__ ef4) {
  int w = __builtin_amdgcn_readfirstlane((int)(threadIdx.x >> 6));
  int be = blockIdx.x * 4 + w;
  int lane = threadIdx.x & 63;
  int b = be / Ee;
  int cA = min(Acnt[be], CAP), cC = min(Ccnt[be], CAP);
  const int* pA = Aidx + (size_t)be * CAP;
  const int* pC = Cidx + (size_t)be * CAP;
  float4 ev = ev4[(size_t)be * 64 + lane];
  float4 sA = ev, sC = ev;
  for (int i = 0; i < cA; ++i) {
    int n = pA[i];
    float4 t = ns4[((size_t)b * Nn + n) * 64 + lane];
    sA.x += t.x; sA.y += t.y; sA.z += t.z; sA.w += t.w;
  }
  for (int i = 0; i < cC; ++i) {
    int n = pC[i];
    float4 t = ns4[((size_t)b * Nn + n) * 64 + lane];
    sC.x += t.x; sC.y += t.y; sC.z += t.z; sC.w += t.w;
  }
  eb4[(size_t)be * 64 + lane] = pack4(sA);
  ef4[(size_t)be * 64 + lane] = pack4(sC);
}

// ---------- per-hop: node aggregation + build GEMM inputs, float4, 4 nodes/block ----------
__global__ void node_kernel(const float4* __restrict__ ns4,
                            const ushort4* __restrict__ eb4, const ushort4* __restrict__ ef4,
                            const int* __restrict__ Bidx, const int* __restrict__ Bcnt,
                            const int* __restrict__ Didx, const int* __restrict__ Dcnt,
                            ushort4* __restrict__ Xfz4, ushort4* __restrict__ Xzr4) {
  int w = __builtin_amdgcn_readfirstlane((int)(threadIdx.x >> 6));
  int bn = blockIdx.x * 4 + w;
  int lane = threadIdx.x & 63;
  int b = bn / Nn;
  int rB = Bcnt[bn], rD = Dcnt[bn];
  int cB = min(rB, CAP), cD = min(rD, CAP);
  const int* pB = Bidx + (size_t)bn * CAP;
  const int* pD = Didx + (size_t)bn * CAP;
  float4 h0 = ns4[(size_t)bn * 64 + lane];
  float4 sb = h0, sf = h0;
  for (int i = 0; i < cB; ++i) {
    int e = pB[i];
    float4 t = unpack4(eb4[((size_t)b * Ee + e) * 64 + lane]);
    sb.x += t.x; sb.y += t.y; sb.z += t.z; sb.w += t.w;
  }
  for (int i = 0; i < cD; ++i) {
    int e = pD[i];
    float4 t = unpack4(ef4[((size_t)b * Ee + e) * 64 + lane]);
    sf.x += t.x; sf.y += t.y; sf.z += t.z; sf.w += t.w;
  }
  float ib = 1.f / (1.f + (float)rB), idf = 1.f / (1.f + (float)rD);
  sb.x *= ib; sb.y *= ib; sb.z *= ib; sb.w *= ib;
  sf.x *= idf; sf.y *= idf; sf.z *= idf; sf.w *= idf;
  float4 prod = make_float4(sf.x*sb.x, sf.y*sb.y, sf.z*sb.z, sf.w*sb.w);
  float4 diff = make_float4(sf.x-sb.x, sf.y-sb.y, sf.z-sb.z, sf.w-sb.w);
  size_t m = bn;
  Xfz4[m * 256 +   0 + lane] = pack4(sf);
  Xfz4[m * 256 +  64 + lane] = pack4(sb);
  Xfz4[m * 256 + 128 + lane] = pack4(prod);
  Xfz4[m * 256 + 192 + lane] = pack4(diff);
  Xzr4[m * 128 + lane] = pack4(h0);
}

// ---------- bf16 MFMA GEMM with fused epilogues ----------
#define EPI_NONE 0
#define EPI_FZ   1
#define EPI_ZR   2
#define EPI_GRU  3

template<int EPI>
__global__ __launch_bounds__(256) void gemm_kernel(
    const unsigned short* __restrict__ A, const unsigned short* __restrict__ WT,
    int M, int Nout, int K,
    float* __restrict__ outf, const float* __restrict__ bfz,
    unsigned short* __restrict__ Xzr, float* __restrict__ zbuf,
    unsigned short* __restrict__ Xt, float* __restrict__ ns)
{
  __shared__ unsigned short As[64][72];
  __shared__ unsigned short Bs[64][72];
  int m0 = blockIdx.x * 64, n0 = blockIdx.y * 64;
  int tid = threadIdx.x;
  int lane = tid & 63, wid = tid >> 6;
  int wm = wid >> 1, wn = wid & 1;
  f32x4 acc[2][2] = {};
  for (int k0 = 0; k0 < K; k0 += 64) {
    #pragma unroll
    for (int s = 0; s < 2; ++s) {
      int chunk = tid + s * 256;     // 0..511
      int row = chunk >> 3;
      int co = (chunk & 7) * 8;
      int gm = m0 + row;
      uint4 va = make_uint4(0, 0, 0, 0);
      if (gm < M) va = *(const uint4*)(A + (size_t)gm * K + k0 + co);
      *(uint4*)(&As[row][co]) = va;
      uint4 vb = *(const uint4*)(WT + (size_t)(n0 + row) * K + k0 + co);
      *(uint4*)(&Bs[row][co]) = vb;
    }
    __syncthreads();
    int ko = (lane >> 4) * 8;
    int ra = wm * 32 + (lane & 15);
    int rb = wn * 32 + (lane & 15);
    #pragma unroll
    for (int kk = 0; kk < 64; kk += 32) {
      bf16x8 a0 = *(const bf16x8*)(&As[ra][kk + ko]);
      bf16x8 a1 = *(const bf16x8*)(&As[ra + 16][kk + ko]);
      bf16x8 b0 = *(const bf16x8*)(&Bs[rb][kk + ko]);
      bf16x8 b1 = *(const bf16x8*)(&Bs[rb + 16][kk + ko]);
      acc[0][0] = __builtin_amdgcn_mfma_f32_16x16x32_bf16(a0, b0, acc[0][0], 0, 0, 0);
      acc[0][1] = __builtin_amdgcn_mfma_f32_16x16x32_bf16(a0, b1, acc[0][1], 0, 0, 0);
      acc[1][0] = __builtin_amdgcn_mfma_f32_16x16x32_bf16(a1, b0, acc[1][0], 0, 0, 0);
      acc[1][1] = __builtin_amdgcn_mfma_f32_16x16x32_bf16(a1, b1, acc[1][1], 0, 0, 0);
    }
    __syncthreads();
  }
  #pragma unroll
  for (int mi = 0; mi < 2; ++mi)
  #pragma unroll
  for (int ni = 0; ni < 2; ++ni)
  #pragma unroll
  for (int j = 0; j < 4; ++j) {
    int m = m0 + wm * 32 + mi * 16 + (lane >> 4) * 4 + j;
    int c = n0 + wn * 32 + ni * 16 + (lane & 15);
    if (m >= M) continue;
    float v = acc[mi][ni][j];
    if (EPI == EPI_NONE) {
      outf[(size_t)m * 256 + c] = v;
    } else if (EPI == EPI_FZ) {
      float z = sigmoidf_(v + bfz[c]);
      float fw = b2f(A[(size_t)m * K + c]);
      float bw = b2f(A[(size_t)m * K + 256 + c]);
      Xzr[(size_t)m * 512 + 256 + c] = f2b((1.f - z) * fw + z * bw);
    } else if (EPI == EPI_ZR) {
      float s = sigmoidf_(v);
      if (c < 256) {
        zbuf[(size_t)m * 256 + c] = s;
        Xt[(size_t)m * 512 + 256 + c] = A[(size_t)m * 512 + 256 + c];  // copy bf16(agg)
      } else {
        int cz = c - 256;
        Xt[(size_t)m * 512 + cz] = f2b(s * ns[(size_t)m * 256 + cz]);  // r*h
      }
    } else { // EPI_GRU
      float t = tanhf(v);
      float zz = zbuf[(size_t)m * 256 + c];
      float h = ns[(size_t)m * 256 + c];
      ns[(size_t)m * 256 + c] = (1.f - zz) * h + zz * t;
    }
  }
}

// ---------- output ----------
__global__ void transpose_out_kernel(const float4* __restrict__ ns4, float4* __restrict__ out4,
                                     ushort4* __restrict__ nsb4) {
  int w = __builtin_amdgcn_readfirstlane((int)(threadIdx.x >> 6));
  int bn = blockIdx.x * 4 + w;
  int lane = threadIdx.x & 63;
  int b = bn / Nn, n = bn % Nn;
  float4 v = ns4[(size_t)bn * 64 + lane];
  out4[((size_t)n * Bb + b) * 64 + lane] = v;
  nsb4[(size_t)bn * 64 + lane] = pack4(v);
}

__global__ void maxpart_kernel(const float* __restrict__ tmp, float* __restrict__ part) {
  int bc = blockIdx.x;             // b*12 + chunk (125 rows each)
  int b = bc / 12, ch = bc % 12;
  int h = threadIdx.x;
  float m = -1e30f;
  int nbase = ch * 125;
  for (int i = 0; i < 125; ++i)
    m = fmaxf(m, tmp[((size_t)b * Nn + nbase + i) * Hh + h]);
  part[(size_t)bc * Hh + h] = m;
}
__global__ void maxfin_kernel(const float* __restrict__ part, float* __restrict__ out) {
  int t = blockIdx.x * 256 + threadIdx.x;   // b*256 + h
  if (t >= Bb * Hh) return;
  int b = t / Hh, h = t % Hh;
  float m = -1e30f;
  for (int c = 0; c < 12; ++c) m = fmaxf(m, part[((size_t)b * 12 + c) * Hh + h]);
  out[(size_t)Nn * Bb * Hh + t] = m;
}

extern "C" void kernel_launch(void* const* d_in, const int* in_sizes, int n_in,
                              void* d_out, int out_size, void* d_ws, size_t ws_size,
                              hipStream_t stream) {
  const float* in_ns   = (const float*)d_in[0];
  const float* in_ev   = (const float*)d_in[1];
  const float* in_n2e  = (const float*)d_in[2];   // (B,E,N)
  const float* in_e2n  = (const float*)d_in[3];   // (B,N,E)
  const float* in_wmax = (const float*)d_in[4];
  const float* in_wfz  = (const float*)d_in[5];
  const float* in_bfz  = (const float*)d_in[6];
  const float* in_wz   = (const float*)d_in[7];
  const float* in_wr   = (const float*)d_in[8];
  const float* in_wt   = (const float*)d_in[9];
  float* out = (float*)d_out;

  char* base = (char*)d_ws;
  size_t off = 0;
  auto alloc = [&](size_t bytes) -> void* {
    void* r = base + off;
    off = (off + bytes + 255) & ~(size_t)255;
    return r;
  };
  int* cntA = (int*)alloc(BE * 4);
  int* Aidx = (int*)alloc((size_t)BE * CAP * 4);
  int* cntB = (int*)alloc(BN * 4);
  int* Bidx = (int*)alloc((size_t)BN * CAP * 4);
  int* cntC = (int*)alloc(BE * 4);
  int* Cidx = (int*)alloc((size_t)BE * CAP * 4);
  int* cntD = (int*)alloc(BN * 4);
  int* Didx = (int*)alloc((size_t)BN * CAP * 4);
  float* ns   = (float*)alloc((size_t)Mrows * Hh * 4);
  unsigned short* eb = (unsigned short*)alloc((size_t)BE * Hh * 2);   // bf16
  unsigned short* ef = (unsigned short*)alloc((size_t)BE * Hh * 2);   // bf16
  float* gout = (float*)alloc((size_t)Mrows * 256 * 4);
  unsigned short* Xfz = (unsigned short*)alloc((size_t)Mrows * 1024 * 2);
  unsigned short* Xzr = (unsigned short*)alloc((size_t)Mrows * 512 * 2);
  unsigned short* Xt  = (unsigned short*)alloc((size_t)Mrows * 512 * 2);
  float* zbuf = (float*)alloc((size_t)Mrows * 256 * 4);
  unsigned short* nsb = (unsigned short*)alloc((size_t)Mrows * 256 * 2);
  float* part = (float*)alloc((size_t)Bb * 12 * Hh * 4);
  unsigned short* WfzT  = (unsigned short*)alloc(256 * 1024 * 2);
  unsigned short* WzrT  = (unsigned short*)alloc(512 * 512 * 2);
  unsigned short* WtT   = (unsigned short*)alloc(256 * 512 * 2);
  unsigned short* WmaxT = (unsigned short*)alloc(256 * 256 * 2);
  (void)ws_size; (void)in_sizes; (void)n_in; (void)out_size;

  hipMemsetAsync(cntC, 0, BE * 4, stream);
  hipMemsetAsync(cntD, 0, BN * 4, stream);
  hipMemcpyAsync(ns, in_ns, (size_t)Mrows * Hh * 4, hipMemcpyDeviceToDevice, stream);

  wtrans_kernel<<<(1024 * 256 + 255) / 256, 256, 0, stream>>>(in_wfz, WfzT, 1024, 256);
  wzr_kernel<<<(512 * 512 + 255) / 256, 256, 0, stream>>>(in_wz, in_wr, WzrT);
  wtrans_kernel<<<(512 * 256 + 255) / 256, 256, 0, stream>>>(in_wt, WtT, 512, 256);
  wtrans_kernel<<<(256 * 256 + 255) / 256, 256, 0, stream>>>(in_wmax, WmaxT, 256, 256);

  // n2e: rows = edges (list A), column scatter -> D (node->edges), colCnt = cntD
  rowscan_kernel<<<(Bb * Ee) / 4, 256, 0, stream>>>(in_n2e, Ee, Nn, Aidx, cntA, Didx, cntD);
  // e2n: rows = nodes (list B), column scatter -> C (edge->nodes), colCnt = cntC
  rowscan_kernel<<<(Bb * Nn) / 4, 256, 0, stream>>>(in_e2n, Nn, Ee, Bidx, cntB, Cidx, cntC);
  sort_kernel<<<(BE + 255) / 256, 256, 0, stream>>>(Cidx, cntC, BE);
  sort_kernel<<<(BN + 255) / 256, 256, 0, stream>>>(Didx, cntD, BN);

  dim3 g1(188, 4), g2(188, 8);
  for (int hop = 0; hop < NHOPS; ++hop) {
    edge_kernel<<<BE / 4, 256, 0, stream>>>((const float4*)in_ev, (const float4*)ns,
        Aidx, cntA, Cidx, cntC, (ushort4*)eb, (ushort4*)ef);
    node_kernel<<<BN / 4, 256, 0, stream>>>((const float4*)ns,
        (const ushort4*)eb, (const ushort4*)ef,
        Bidx, cntB, Didx, cntD, (ushort4*)Xfz, (ushort4*)Xzr);
    gemm_kernel<EPI_FZ><<<g1, 256, 0, stream>>>(Xfz, WfzT, Mrows, 256, 1024,
        nullptr, in_bfz, Xzr, nullptr, nullptr, nullptr);
    gemm_kernel<EPI_ZR><<<g2, 256, 0, stream>>>(Xzr, WzrT, Mrows, 512, 512,
        nullptr, nullptr, nullptr, zbuf, Xt, ns);
    gemm_kernel<EPI_GRU><<<g1, 256, 0, stream>>>(Xt, WtT, Mrows, 256, 512,
        nullptr, nullptr, nullptr, zbuf, nullptr, ns);
  }

  transpose_out_kernel<<<BN / 4, 256, 0, stream>>>((const float4*)ns, (float4*)out,
                                                   (ushort4*)nsb);
  gemm_kernel<EPI_NONE><<<g1, 256, 0, stream>>>(nsb, WmaxT, Mrows, 256, 256,
      gout, nullptr, nullptr, nullptr, nullptr, nullptr);
  maxpart_kernel<<<Bb * 12, 256, 0, stream>>>(gout, part);
  maxfin_kernel<<<(Bb * Hh + 255) / 256, 256, 0, stream>>>(part, out);
}

// Round 3
// 471.170 us; speedup vs baseline: 1.4703x; 1.1124x over previous
//
#include <hip/hip_runtime.h>
#include <hip/hip_bf16.h>
#include <stdint.h>

#define Bb 8
#define Nn 1500
#define Ee 3000
#define Hh 256
#define NHOPS 3
#define CAP 32
#define Mrows (Bb*Nn)      // 12000
#define BE (Bb*Ee)         // 24000
#define BN (Bb*Nn)         // 12000

typedef __bf16 bf16x8 __attribute__((ext_vector_type(8)));
typedef float f32x4 __attribute__((ext_vector_type(4)));

__device__ __forceinline__ float sigmoidf_(float x){ return 1.f/(1.f+__expf(-x)); }

__device__ __forceinline__ unsigned short f2b(float f){
  union { float f; unsigned int u; } x; x.f = f;
  unsigned int r = (x.u + 0x7fffu + ((x.u >> 16) & 1u)) >> 16;
  return (unsigned short)r;
}
__device__ __forceinline__ float b2f(unsigned short u){
  union { unsigned int u; float f; } x; x.u = ((unsigned int)u) << 16;
  return x.f;
}
__device__ __forceinline__ ushort4 pack4(float4 v){
  return make_ushort4(f2b(v.x), f2b(v.y), f2b(v.z), f2b(v.w));
}
__device__ __forceinline__ float4 unpack4(ushort4 u){
  return make_float4(b2f(u.x), b2f(u.y), b2f(u.z), b2f(u.w));
}

// async global->LDS, 16B per lane; LDS dest = uniform base + lane*16
#define GLL16(g, l) __builtin_amdgcn_global_load_lds( \
    (const __attribute__((address_space(1))) unsigned int*)(g), \
    (__attribute__((address_space(3))) unsigned int*)(l), 16, 0, 0)

// ---------- preprocess: float4 row scan (4-ballot compaction) + atomic column scatter ----------
__global__ void rowscan_kernel(const float* __restrict__ mat, int R, int C,
                               int* __restrict__ rowIdx, int* __restrict__ rowCnt,
                               int* __restrict__ colIdx, int* __restrict__ colCnt) {
  int w = __builtin_amdgcn_readfirstlane((int)(threadIdx.x >> 6));
  int g = blockIdx.x * 4 + w;
  if (g >= Bb * R) return;
  int b = g / R;
  int lane = threadIdx.x & 63;
  const float4* base = (const float4*)(mat + (size_t)g * C);
  int nq = C >> 2;                 // float4 per row (C % 4 == 0)
  int cnt = 0;
  for (int q0 = 0; q0 < nq; q0 += 64) {
    int q = q0 + lane;
    float4 v = make_float4(0.f, 0.f, 0.f, 0.f);
    if (q < nq) v = base[q];
    unsigned long long m0 = __ballot(v.x != 0.f);
    unsigned long long m1 = __ballot(v.y != 0.f);
    unsigned long long m2 = __ballot(v.z != 0.f);
    unsigned long long m3 = __ballot(v.w != 0.f);
    unsigned long long below = (1ull << lane) - 1ull;
    int myc = cnt + __popcll(m0 & below) + __popcll(m1 & below)
                  + __popcll(m2 & below) + __popcll(m3 & below);
    int c = q * 4;
    #pragma unroll
    for (int j = 0; j < 4; ++j) {
      float vv = (j == 0) ? v.x : (j == 1) ? v.y : (j == 2) ? v.z : v.w;
      if (vv != 0.f) {
        if (myc < CAP) rowIdx[(size_t)g * CAP + myc] = c + j;
        int slot = atomicAdd(&colCnt[b * C + c + j], 1);
        if (slot < CAP) colIdx[(size_t)(b * C + c + j) * CAP + slot] = g - b * R;
        ++myc;
      }
    }
    cnt += __popcll(m0) + __popcll(m1) + __popcll(m2) + __popcll(m3);
  }
  if (lane == 0) rowCnt[g] = cnt;
}

__device__ __forceinline__ void sort_one(int* pp, int c) {
  if (c > CAP) c = CAP;
  int v[CAP];
  for (int j = 0; j < c; ++j) v[j] = pp[j];
  for (int j = 1; j < c; ++j) { int key = v[j]; int k = j - 1;
    while (k >= 0 && v[k] > key) { v[k+1] = v[k]; --k; } v[k+1] = key; }
  for (int j = 0; j < c; ++j) pp[j] = v[j];
}
__global__ void sort2_kernel(int* __restrict__ Cidx, const int* __restrict__ cntC,
                             int* __restrict__ Didx, const int* __restrict__ cntD) {
  int i = blockIdx.x * 256 + threadIdx.x;
  if (i < BE) sort_one(Cidx + (size_t)i * CAP, cntC[i]);
  else if (i < BE + BN) { int k = i - BE; sort_one(Didx + (size_t)k * CAP, cntD[k]); }
}

// ---------- merged weight transposes to bf16 (W^T layout [Nout][K]) ----------
__global__ void wprep_kernel(const float* __restrict__ Wfz, const float* __restrict__ Wz,
                             const float* __restrict__ Wr, const float* __restrict__ Wt,
                             const float* __restrict__ Wmax,
                             unsigned short* __restrict__ WfzT, unsigned short* __restrict__ WzrT,
                             unsigned short* __restrict__ WtT, unsigned short* __restrict__ WmaxT) {
  int t = blockIdx.x * 256 + threadIdx.x;
  if (t < 262144) {                       // WfzT: 256 n x 1024 k
    int n = t >> 10, k = t & 1023;
    WfzT[t] = f2b(Wfz[k * 256 + n]);
  } else if (t < 524288) {                // WzrT: 512 j x 512 k
    int u = t - 262144;
    int j = u >> 9, k = u & 511;
    float v = (j < 256) ? Wz[k * 256 + j] : Wr[k * 256 + (j - 256)];
    WzrT[u] = f2b(v);
  } else if (t < 655360) {                // WtT: 256 n x 512 k
    int u = t - 524288;
    int n = u >> 9, k = u & 511;
    WtT[u] = f2b(Wt[k * 256 + n]);
  } else if (t < 720896) {                // WmaxT: 256 x 256
    int u = t - 655360;
    int n = u >> 8, k = u & 255;
    WmaxT[u] = f2b(Wmax[k * 256 + n]);
  }
}

// ---------- per-hop: edge embedding (both directions), float4, 4 edges/block ----------
__global__ void edge_kernel(const float4* __restrict__ ev4, const float4* __restrict__ ns4,
                            const int* __restrict__ Aidx, const int* __restrict__ Acnt,
                            const int* __restrict__ Cidx, const int* __restrict__ Ccnt,
                            ushort4* __restrict__ eb4, ushort4* __restrict__ ef4) {
  int w = __builtin_amdgcn_readfirstlane((int)(threadIdx.x >> 6));
  int be = blockIdx.x * 4 + w;
  int lane = threadIdx.x & 63;
  int b = be / Ee;
  int cA = min(Acnt[be], CAP), cC = min(Ccnt[be], CAP);
  const int* pA = Aidx + (size_t)be * CAP;
  const int* pC = Cidx + (size_t)be * CAP;
  float4 ev = ev4[(size_t)be * 64 + lane];
  float4 sA = ev, sC = ev;
  for (int i = 0; i < cA; ++i) {
    int n = pA[i];
    float4 t = ns4[((size_t)b * Nn + n) * 64 + lane];
    sA.x += t.x; sA.y += t.y; sA.z += t.z; sA.w += t.w;
  }
  for (int i = 0; i < cC; ++i) {
    int n = pC[i];
    float4 t = ns4[((size_t)b * Nn + n) * 64 + lane];
    sC.x += t.x; sC.y += t.y; sC.z += t.z; sC.w += t.w;
  }
  eb4[(size_t)be * 64 + lane] = pack4(sA);
  ef4[(size_t)be * 64 + lane] = pack4(sC);
}

// ---------- per-hop: node aggregation + build GEMM inputs, float4, 4 nodes/block ----------
__global__ void node_kernel(const float4* __restrict__ ns4,
                            const ushort4* __restrict__ eb4, const ushort4* __restrict__ ef4,
                            const int* __restrict__ Bidx, const int* __restrict__ Bcnt,
                            const int* __restrict__ Didx, const int* __restrict__ Dcnt,
                            ushort4* __restrict__ Xfz4, ushort4* __restrict__ Xzr4) {
  int w = __builtin_amdgcn_readfirstlane((int)(threadIdx.x >> 6));
  int bn = blockIdx.x * 4 + w;
  int lane = threadIdx.x & 63;
  int b = bn / Nn;
  int rB = Bcnt[bn], rD = Dcnt[bn];
  int cB = min(rB, CAP), cD = min(rD, CAP);
  const int* pB = Bidx + (size_t)bn * CAP;
  const int* pD = Didx + (size_t)bn * CAP;
  float4 h0 = ns4[(size_t)bn * 64 + lane];
  float4 sb = h0, sf = h0;
  for (int i = 0; i < cB; ++i) {
    int e = pB[i];
    float4 t = unpack4(eb4[((size_t)b * Ee + e) * 64 + lane]);
    sb.x += t.x; sb.y += t.y; sb.z += t.z; sb.w += t.w;
  }
  for (int i = 0; i < cD; ++i) {
    int e = pD[i];
    float4 t = unpack4(ef4[((size_t)b * Ee + e) * 64 + lane]);
    sf.x += t.x; sf.y += t.y; sf.z += t.z; sf.w += t.w;
  }
  float ib = 1.f / (1.f + (float)rB), idf = 1.f / (1.f + (float)rD);
  sb.x *= ib; sb.y *= ib; sb.z *= ib; sb.w *= ib;
  sf.x *= idf; sf.y *= idf; sf.z *= idf; sf.w *= idf;
  float4 prod = make_float4(sf.x*sb.x, sf.y*sb.y, sf.z*sb.z, sf.w*sb.w);
  float4 diff = make_float4(sf.x-sb.x, sf.y-sb.y, sf.z-sb.z, sf.w-sb.w);
  size_t m = bn;
  Xfz4[m * 256 +   0 + lane] = pack4(sf);
  Xfz4[m * 256 +  64 + lane] = pack4(sb);
  Xfz4[m * 256 + 128 + lane] = pack4(prod);
  Xfz4[m * 256 + 192 + lane] = pack4(diff);
  Xzr4[m * 128 + lane] = pack4(h0);
}

// ---------- bf16 MFMA GEMM (m97-class: global_load_lds + XOR chunk swizzle) ----------
// Tile: BM=128, BN=64, BK=64, 512 threads (8 waves, 4x2), each wave 32x32 out.
// LDS linear [row][64] bf16 with chunk-XOR layout: chunk stored at (q ^ (row&7)).
// global_load_lds writes linearly; source address applies the same involution.
#define EPI_NONE 0
#define EPI_FZ   1
#define EPI_ZR   2
#define EPI_GRU  3

template<int EPI>
__global__ __launch_bounds__(512) void gemm_kernel(
    const unsigned short* __restrict__ A, const unsigned short* __restrict__ WT,
    int M, int K,
    float* __restrict__ outf, const float* __restrict__ bfz,
    unsigned short* __restrict__ Xzr, unsigned short* __restrict__ zbuf,
    unsigned short* __restrict__ Xt, float* __restrict__ ns)
{
  __shared__ unsigned short As[128 * 64];
  __shared__ unsigned short Bs[64 * 64];
  int m0 = blockIdx.x * 128, n0 = blockIdx.y * 64;
  int tid = threadIdx.x;
  int lane = tid & 63;
  int wid = __builtin_amdgcn_readfirstlane(tid >> 6);
  int wm = wid >> 1, wn = wid & 1;          // wave grid 4x2
  int p = lane >> 4;                        // quarter-wave
  int q = lane & 7;                         // 16B chunk within row
  int lr = lane >> 3;                       // row within 8-row stage group
  f32x4 acc[2][2] = {};
  for (int k0 = 0; k0 < K; k0 += 64) {
    // stage: per wave 2x A (16 rows) + 1x B (8 rows), 16B/lane, linear LDS dest
    {
      int rl0 = wid * 16 + lr;
      int gm0 = m0 + rl0; if (gm0 > M - 1) gm0 = M - 1;
      GLL16(A + (size_t)gm0 * K + k0 + ((q ^ (rl0 & 7)) << 3), &As[(wid * 16) * 64]);
      int rl1 = rl0 + 8;
      int gm1 = m0 + rl1; if (gm1 > M - 1) gm1 = M - 1;
      GLL16(A + (size_t)gm1 * K + k0 + ((q ^ (rl1 & 7)) << 3), &As[(wid * 16 + 8) * 64]);
      int rb = wid * 8 + lr;
      GLL16(WT + (size_t)(n0 + rb) * K + k0 + ((q ^ (rb & 7)) << 3), &Bs[(wid * 8) * 64]);
    }
    __syncthreads();
    #pragma unroll
    for (int kk = 0; kk < 64; kk += 32) {
      int cq = (kk >> 3) + p;               // chunk index 0..7
      int ra0 = wm * 32 + (lane & 15);
      int ra1 = ra0 + 16;
      int rb0 = wn * 32 + (lane & 15);
      int rb1 = rb0 + 16;
      bf16x8 a0 = *(const bf16x8*)&As[ra0 * 64 + ((cq ^ (ra0 & 7)) << 3)];
      bf16x8 a1 = *(const bf16x8*)&As[ra1 * 64 + ((cq ^ (ra1 & 7)) << 3)];
      bf16x8 b0 = *(const bf16x8*)&Bs[rb0 * 64 + ((cq ^ (rb0 & 7)) << 3)];
      bf16x8 b1 = *(const bf16x8*)&Bs[rb1 * 64 + ((cq ^ (rb1 & 7)) << 3)];
      acc[0][0] = __builtin_amdgcn_mfma_f32_16x16x32_bf16(a0, b0, acc[0][0], 0, 0, 0);
      acc[0][1] = __builtin_amdgcn_mfma_f32_16x16x32_bf16(a0, b1, acc[0][1], 0, 0, 0);
      acc[1][0] = __builtin_amdgcn_mfma_f32_16x16x32_bf16(a1, b0, acc[1][0], 0, 0, 0);
      acc[1][1] = __builtin_amdgcn_mfma_f32_16x16x32_bf16(a1, b1, acc[1][1], 0, 0, 0);
    }
    __syncthreads();
  }
  #pragma unroll
  for (int mi = 0; mi < 2; ++mi)
  #pragma unroll
  for (int ni = 0; ni < 2; ++ni)
  #pragma unroll
  for (int j = 0; j < 4; ++j) {
    int m = m0 + wm * 32 + mi * 16 + p * 4 + j;
    int c = n0 + wn * 32 + ni * 16 + (lane & 15);
    if (m >= M) continue;
    float v = acc[mi][ni][j];
    if (EPI == EPI_NONE) {
      outf[(size_t)m * 256 + c] = v;
    } else if (EPI == EPI_FZ) {
      float z = sigmoidf_(v + bfz[c]);
      float fw = b2f(A[(size_t)m * K + c]);
      float bw = b2f(A[(size_t)m * K + 256 + c]);
      Xzr[(size_t)m * 512 + 256 + c] = f2b((1.f - z) * fw + z * bw);
    } else if (EPI == EPI_ZR) {
      float s = sigmoidf_(v);
      if (c < 256) {
        zbuf[(size_t)m * 256 + c] = f2b(s);
        Xt[(size_t)m * 512 + 256 + c] = A[(size_t)m * 512 + 256 + c];  // copy bf16(agg)
      } else {
        int cz = c - 256;
        Xt[(size_t)m * 512 + cz] = f2b(s * ns[(size_t)m * 256 + cz]);  // r*h
      }
    } else { // EPI_GRU
      float t = tanhf(v);
      float zz = b2f(zbuf[(size_t)m * 256 + c]);
      float h = ns[(size_t)m * 256 + c];
      ns[(size_t)m * 256 + c] = (1.f - zz) * h + zz * t;
    }
  }
}

// ---------- output ----------
__global__ void transpose_out_kernel(const float4* __restrict__ ns4, float4* __restrict__ out4,
                                     ushort4* __restrict__ nsb4) {
  int w = __builtin_amdgcn_readfirstlane((int)(threadIdx.x >> 6));
  int bn = blockIdx.x * 4 + w;
  int lane = threadIdx.x & 63;
  int b = bn / Nn, n = bn % Nn;
  float4 v = ns4[(size_t)bn * 64 + lane];
  out4[((size_t)n * Bb + b) * 64 + lane] = v;
  nsb4[(size_t)bn * 64 + lane] = pack4(v);
}

__global__ void maxpart_kernel(const float* __restrict__ tmp, float* __restrict__ part) {
  int bc = blockIdx.x;             // b*12 + chunk (125 rows each)
  int b = bc / 12, ch = bc % 12;
  int h = threadIdx.x;
  float m = -1e30f;
  int nbase = ch * 125;
  for (int i = 0; i < 125; ++i)
    m = fmaxf(m, tmp[((size_t)b * Nn + nbase + i) * Hh + h]);
  part[(size_t)bc * Hh + h] = m;
}
__global__ void maxfin_kernel(const float* __restrict__ part, float* __restrict__ out) {
  int t = blockIdx.x * 256 + threadIdx.x;   // b*256 + h
  if (t >= Bb * Hh) return;
  int b = t / Hh, h = t % Hh;
  float m = -1e30f;
  for (int c = 0; c < 12; ++c) m = fmaxf(m, part[((size_t)b * 12 + c) * Hh + h]);
  out[(size_t)Nn * Bb * Hh + t] = m;
}

extern "C" void kernel_launch(void* const* d_in, const int* in_sizes, int n_in,
                              void* d_out, int out_size, void* d_ws, size_t ws_size,
                              hipStream_t stream) {
  const float* in_ns   = (const float*)d_in[0];
  const float* in_ev   = (const float*)d_in[1];
  const float* in_n2e  = (const float*)d_in[2];   // (B,E,N)
  const float* in_e2n  = (const float*)d_in[3];   // (B,N,E)
  const float* in_wmax = (const float*)d_in[4];
  const float* in_wfz  = (const float*)d_in[5];
  const float* in_bfz  = (const float*)d_in[6];
  const float* in_wz   = (const float*)d_in[7];
  const float* in_wr   = (const float*)d_in[8];
  const float* in_wt   = (const float*)d_in[9];
  float* out = (float*)d_out;

  char* base = (char*)d_ws;
  size_t off = 0;
  auto alloc = [&](size_t bytes) -> void* {
    void* r = base + off;
    off = (off + bytes + 255) & ~(size_t)255;
    return r;
  };
  int* cntA = (int*)alloc(BE * 4);
  int* Aidx = (int*)alloc((size_t)BE * CAP * 4);
  int* cntB = (int*)alloc(BN * 4);
  int* Bidx = (int*)alloc((size_t)BN * CAP * 4);
  int* cntC = (int*)alloc(BE * 4);
  int* Cidx = (int*)alloc((size_t)BE * CAP * 4);
  int* cntD = (int*)alloc(BN * 4);
  int* Didx = (int*)alloc((size_t)BN * CAP * 4);
  float* ns   = (float*)alloc((size_t)Mrows * Hh * 4);
  unsigned short* eb = (unsigned short*)alloc((size_t)BE * Hh * 2);   // bf16
  unsigned short* ef = (unsigned short*)alloc((size_t)BE * Hh * 2);   // bf16
  float* gout = (float*)alloc((size_t)Mrows * 256 * 4);
  unsigned short* Xfz = (unsigned short*)alloc((size_t)Mrows * 1024 * 2);
  unsigned short* Xzr = (unsigned short*)alloc((size_t)Mrows * 512 * 2);
  unsigned short* Xt  = (unsigned short*)alloc((size_t)Mrows * 512 * 2);
  unsigned short* zbuf = (unsigned short*)alloc((size_t)Mrows * 256 * 2); // bf16
  unsigned short* nsb = (unsigned short*)alloc((size_t)Mrows * 256 * 2);
  float* part = (float*)alloc((size_t)Bb * 12 * Hh * 4);
  unsigned short* WfzT  = (unsigned short*)alloc(256 * 1024 * 2);
  unsigned short* WzrT  = (unsigned short*)alloc(512 * 512 * 2);
  unsigned short* WtT   = (unsigned short*)alloc(256 * 512 * 2);
  unsigned short* WmaxT = (unsigned short*)alloc(256 * 256 * 2);
  (void)ws_size; (void)in_sizes; (void)n_in; (void)out_size;

  hipMemsetAsync(cntC, 0, BE * 4, stream);
  hipMemsetAsync(cntD, 0, BN * 4, stream);
  hipMemcpyAsync(ns, in_ns, (size_t)Mrows * Hh * 4, hipMemcpyDeviceToDevice, stream);

  wprep_kernel<<<2816, 256, 0, stream>>>(in_wfz, in_wz, in_wr, in_wt, in_wmax,
                                         WfzT, WzrT, WtT, WmaxT);

  // n2e: rows = edges (list A), column scatter -> D (node->edges), colCnt = cntD
  rowscan_kernel<<<(Bb * Ee) / 4, 256, 0, stream>>>(in_n2e, Ee, Nn, Aidx, cntA, Didx, cntD);
  // e2n: rows = nodes (list B), column scatter -> C (edge->nodes), colCnt = cntC
  rowscan_kernel<<<(Bb * Nn) / 4, 256, 0, stream>>>(in_e2n, Nn, Ee, Bidx, cntB, Cidx, cntC);
  sort2_kernel<<<(BE + BN + 255) / 256, 256, 0, stream>>>(Cidx, cntC, Didx, cntD);

  dim3 gFZ(94, 4), gZR(94, 8), gT(94, 4);
  for (int hop = 0; hop < NHOPS; ++hop) {
    edge_kernel<<<BE / 4, 256, 0, stream>>>((const float4*)in_ev, (const float4*)ns,
        Aidx, cntA, Cidx, cntC, (ushort4*)eb, (ushort4*)ef);
    node_kernel<<<BN / 4, 256, 0, stream>>>((const float4*)ns,
        (const ushort4*)eb, (const ushort4*)ef,
        Bidx, cntB, Didx, cntD, (ushort4*)Xfz, (ushort4*)Xzr);
    gemm_kernel<EPI_FZ><<<gFZ, 512, 0, stream>>>(Xfz, WfzT, Mrows, 1024,
        nullptr, in_bfz, Xzr, nullptr, nullptr, nullptr);
    gemm_kernel<EPI_ZR><<<gZR, 512, 0, stream>>>(Xzr, WzrT, Mrows, 512,
        nullptr, nullptr, nullptr, zbuf, Xt, ns);
    gemm_kernel<EPI_GRU><<<gT, 512, 0, stream>>>(Xt, WtT, Mrows, 512,
        nullptr, nullptr, nullptr, zbuf, nullptr, ns);
  }

  transpose_out_kernel<<<BN / 4, 256, 0, stream>>>((const float4*)ns, (float4*)out,
                                                   (ushort4*)nsb);
  gemm_kernel<EPI_NONE><<<gT, 512, 0, stream>>>(nsb, WmaxT, Mrows, 256,
      gout, nullptr, nullptr, nullptr, nullptr, nullptr);
  maxpart_kernel<<<Bb * 12, 256, 0, stream>>>(gout, part);
  maxfin_kernel<<<(Bb * Hh + 255) / 256, 256, 0, stream>>>(part, out);
}

// Round 4
// 437.452 us; speedup vs baseline: 1.5836x; 1.0771x over previous
//
#include <hip/hip_runtime.h>
#include <hip/hip_bf16.h>
#include <stdint.h>

#define Bb 8
#define Nn 1500
#define Ee 3000
#define Hh 256
#define NHOPS 3
#define CAP 32
#define Mrows (Bb*Nn)      // 12000
#define BE (Bb*Ee)         // 24000
#define BN (Bb*Nn)         // 12000

typedef __bf16 bf16x8 __attribute__((ext_vector_type(8)));
typedef float f32x4 __attribute__((ext_vector_type(4)));

__device__ __forceinline__ float sigmoidf_(float x){ return 1.f/(1.f+__expf(-x)); }

__device__ __forceinline__ unsigned short f2b(float f){
  union { float f; unsigned int u; } x; x.f = f;
  unsigned int r = (x.u + 0x7fffu + ((x.u >> 16) & 1u)) >> 16;
  return (unsigned short)r;
}
__device__ __forceinline__ float b2f(unsigned short u){
  union { unsigned int u; float f; } x; x.u = ((unsigned int)u) << 16;
  return x.f;
}
__device__ __forceinline__ ushort4 pack4(float4 v){
  return make_ushort4(f2b(v.x), f2b(v.y), f2b(v.z), f2b(v.w));
}
__device__ __forceinline__ float4 unpack4(ushort4 u){
  return make_float4(b2f(u.x), b2f(u.y), b2f(u.z), b2f(u.w));
}

// async global->LDS, 16B per lane; LDS dest = uniform base + lane*16
#define GLL16(g, l) __builtin_amdgcn_global_load_lds( \
    (const __attribute__((address_space(1))) unsigned int*)(g), \
    (__attribute__((address_space(3))) unsigned int*)(l), 16, 0, 0)

// ---------- preprocess megakernel ----------
// sections (256 threads/block):
//  [0,6000)        rowscan n2e (4 rows/block, R=Ee, C=Nn)
//  [6000,9000)     rowscan e2n (R=Nn, C=Ee)
//  [9000,11560)    weight prep (655360 elems)
//  [11560,14560)   ns copy f32 (float4)
//  [14560,16060)   edge_vec f32 -> bf16 (4 float4/thread)
__device__ __forceinline__ void rowscan_body(const float* __restrict__ mat, int R, int C,
                                             int* __restrict__ rowIdx, int* __restrict__ rowCnt,
                                             int* __restrict__ colIdx, int* __restrict__ colCnt,
                                             int blk) {
  int w = __builtin_amdgcn_readfirstlane((int)(threadIdx.x >> 6));
  int g = blk * 4 + w;
  if (g >= Bb * R) return;
  int b = g / R;
  int lane = threadIdx.x & 63;
  const float4* base = (const float4*)(mat + (size_t)g * C);
  int nq = C >> 2;
  int cnt = 0;
  for (int q0 = 0; q0 < nq; q0 += 64) {
    int q = q0 + lane;
    float4 v = make_float4(0.f, 0.f, 0.f, 0.f);
    if (q < nq) v = base[q];
    unsigned long long m0 = __ballot(v.x != 0.f);
    unsigned long long m1 = __ballot(v.y != 0.f);
    unsigned long long m2 = __ballot(v.z != 0.f);
    unsigned long long m3 = __ballot(v.w != 0.f);
    unsigned long long below = (1ull << lane) - 1ull;
    int myc = cnt + __popcll(m0 & below) + __popcll(m1 & below)
                  + __popcll(m2 & below) + __popcll(m3 & below);
    int c = q * 4;
    #pragma unroll
    for (int j = 0; j < 4; ++j) {
      float vv = (j == 0) ? v.x : (j == 1) ? v.y : (j == 2) ? v.z : v.w;
      if (vv != 0.f) {
        if (myc < CAP) rowIdx[(size_t)g * CAP + myc] = c + j;
        int slot = atomicAdd(&colCnt[b * C + c + j], 1);
        if (slot < CAP) colIdx[(size_t)(b * C + c + j) * CAP + slot] = g - b * R;
        ++myc;
      }
    }
    cnt += __popcll(m0) + __popcll(m1) + __popcll(m2) + __popcll(m3);
  }
  if (lane == 0) rowCnt[g] = cnt;
}

__global__ void preprocess_kernel(const float* __restrict__ n2e, const float* __restrict__ e2n,
                                  int* __restrict__ Aidx, int* __restrict__ cntA,
                                  int* __restrict__ Didx, int* __restrict__ cntD,
                                  int* __restrict__ Bidx, int* __restrict__ cntB,
                                  int* __restrict__ Cidx, int* __restrict__ cntC,
                                  const float* __restrict__ Wfz, const float* __restrict__ Wz,
                                  const float* __restrict__ Wr, const float* __restrict__ Wt,
                                  const float* __restrict__ Wmax,
                                  unsigned short* __restrict__ WfzT, unsigned short* __restrict__ WzrT,
                                  unsigned short* __restrict__ WtT, unsigned short* __restrict__ WmaxT,
                                  const float* __restrict__ in_ns, float* __restrict__ ns,
                                  const float* __restrict__ in_ev, unsigned short* __restrict__ evb) {
  int bx = blockIdx.x;
  if (bx < 6000) {
    rowscan_body(n2e, Ee, Nn, Aidx, cntA, Didx, cntD, bx);
  } else if (bx < 9000) {
    rowscan_body(e2n, Nn, Ee, Bidx, cntB, Cidx, cntC, bx - 6000);
  } else if (bx < 11560) {
    int t = (bx - 9000) * 256 + threadIdx.x;
    if (t < 196608) {                       // WfzT': 256 n x 768 k (combined)
      int n = t / 768, k = t % 768;
      float v;
      if (k < 256)      v = Wfz[k * 256 + n] + Wfz[(k + 768) * 256 + n];
      else if (k < 512) v = Wfz[k * 256 + n] - Wfz[(k + 512) * 256 + n];
      else              v = Wfz[k * 256 + n];
      WfzT[t] = f2b(v);
    } else if (t < 458752) {                // WzrT: 512 j x 512 k
      int u = t - 196608;
      int j = u >> 9, k = u & 511;
      float v = (j < 256) ? Wz[k * 256 + j] : Wr[k * 256 + (j - 256)];
      WzrT[u] = f2b(v);
    } else if (t < 589824) {                // WtT: 256 n x 512 k
      int u = t - 458752;
      int n = u >> 9, k = u & 511;
      WtT[u] = f2b(Wt[k * 256 + n]);
    } else if (t < 655360) {                // WmaxT: 256 x 256
      int u = t - 589824;
      int n = u >> 8, k = u & 255;
      WmaxT[u] = f2b(Wmax[k * 256 + n]);
    }
  } else if (bx < 14560) {
    int t = (bx - 11560) * 256 + threadIdx.x;   // 768000 float4
    ((float4*)ns)[t] = ((const float4*)in_ns)[t];
  } else {
    int t0 = (bx - 14560) * 1024 + threadIdx.x; // 1536000 float4, 4 per thread
    #pragma unroll
    for (int r = 0; r < 4; ++r) {
      int t = t0 + r * 256;
      ((ushort4*)evb)[t] = pack4(((const float4*)in_ev)[t]);
    }
  }
}

__device__ __forceinline__ void sort_one(int* pp, int c) {
  if (c > CAP) c = CAP;
  int v[CAP];
  for (int j = 0; j < c; ++j) v[j] = pp[j];
  for (int j = 1; j < c; ++j) { int key = v[j]; int k = j - 1;
    while (k >= 0 && v[k] > key) { v[k+1] = v[k]; --k; } v[k+1] = key; }
  for (int j = 0; j < c; ++j) pp[j] = v[j];
}
__global__ void sort2_kernel(int* __restrict__ Cidx, const int* __restrict__ cntC,
                             int* __restrict__ Didx, const int* __restrict__ cntD) {
  int i = blockIdx.x * 256 + threadIdx.x;
  if (i < BE) sort_one(Cidx + (size_t)i * CAP, cntC[i]);
  else if (i < BE + BN) { int k = i - BE; sort_one(Didx + (size_t)k * CAP, cntD[k]); }
}

// ---------- per-hop: edge embedding (both directions), 4 edges/block ----------
__global__ void edge_kernel(const ushort4* __restrict__ evb4, const float4* __restrict__ ns4,
                            const int* __restrict__ Aidx, const int* __restrict__ Acnt,
                            const int* __restrict__ Cidx, const int* __restrict__ Ccnt,
                            ushort4* __restrict__ eb4, ushort4* __restrict__ ef4) {
  int w = __builtin_amdgcn_readfirstlane((int)(threadIdx.x >> 6));
  int be = blockIdx.x * 4 + w;
  int lane = threadIdx.x & 63;
  int b = be / Ee;
  int cA = min(Acnt[be], CAP), cC = min(Ccnt[be], CAP);
  const int* pA = Aidx + (size_t)be * CAP;
  const int* pC = Cidx + (size_t)be * CAP;
  float4 ev = unpack4(evb4[(size_t)be * 64 + lane]);
  float4 sA = ev, sC = ev;
  for (int i = 0; i < cA; ++i) {
    int n = pA[i];
    float4 t = ns4[((size_t)b * Nn + n) * 64 + lane];
    sA.x += t.x; sA.y += t.y; sA.z += t.z; sA.w += t.w;
  }
  for (int i = 0; i < cC; ++i) {
    int n = pC[i];
    float4 t = ns4[((size_t)b * Nn + n) * 64 + lane];
    sC.x += t.x; sC.y += t.y; sC.z += t.z; sC.w += t.w;
  }
  eb4[(size_t)be * 64 + lane] = pack4(sA);
  ef4[(size_t)be * 64 + lane] = pack4(sC);
}

// ---------- per-hop: node aggregation + build GEMM inputs ----------
__global__ void node_kernel(const float4* __restrict__ ns4,
                            const ushort4* __restrict__ eb4, const ushort4* __restrict__ ef4,
                            const int* __restrict__ Bidx, const int* __restrict__ Bcnt,
                            const int* __restrict__ Didx, const int* __restrict__ Dcnt,
                            ushort4* __restrict__ Xfz4, ushort4* __restrict__ Xzr4) {
  int w = __builtin_amdgcn_readfirstlane((int)(threadIdx.x >> 6));
  int bn = blockIdx.x * 4 + w;
  int lane = threadIdx.x & 63;
  int b = bn / Nn;
  int rB = Bcnt[bn], rD = Dcnt[bn];
  int cB = min(rB, CAP), cD = min(rD, CAP);
  const int* pB = Bidx + (size_t)bn * CAP;
  const int* pD = Didx + (size_t)bn * CAP;
  float4 h0 = ns4[(size_t)bn * 64 + lane];
  float4 sb = h0, sf = h0;
  for (int i = 0; i < cB; ++i) {
    int e = pB[i];
    float4 t = unpack4(eb4[((size_t)b * Ee + e) * 64 + lane]);
    sb.x += t.x; sb.y += t.y; sb.z += t.z; sb.w += t.w;
  }
  for (int i = 0; i < cD; ++i) {
    int e = pD[i];
    float4 t = unpack4(ef4[((size_t)b * Ee + e) * 64 + lane]);
    sf.x += t.x; sf.y += t.y; sf.z += t.z; sf.w += t.w;
  }
  float ib = 1.f / (1.f + (float)rB), idf = 1.f / (1.f + (float)rD);
  sb.x *= ib; sb.y *= ib; sb.z *= ib; sb.w *= ib;
  sf.x *= idf; sf.y *= idf; sf.z *= idf; sf.w *= idf;
  float4 prod = make_float4(sf.x*sb.x, sf.y*sb.y, sf.z*sb.z, sf.w*sb.w);
  size_t m = bn;
  Xfz4[m * 192 +   0 + lane] = pack4(sf);
  Xfz4[m * 192 +  64 + lane] = pack4(sb);
  Xfz4[m * 192 + 128 + lane] = pack4(prod);
  Xzr4[m * 128 + lane] = pack4(h0);
}

// ---------- bf16 MFMA GEMM (m97-class: global_load_lds + XOR chunk swizzle) ----------
#define EPI_NONE 0
#define EPI_FZ   1
#define EPI_ZR   2
#define EPI_GRU  3

template<int EPI>
__global__ __launch_bounds__(512) void gemm_kernel(
    const unsigned short* __restrict__ A, const unsigned short* __restrict__ WT,
    int M, int K,
    float* __restrict__ outf, const float* __restrict__ bfz,
    unsigned short* __restrict__ Xzr, unsigned short* __restrict__ zbuf,
    unsigned short* __restrict__ Xt, float* __restrict__ ns)
{
  __shared__ unsigned short As[128 * 64];
  __shared__ unsigned short Bs[64 * 64];
  int m0 = blockIdx.x * 128, n0 = blockIdx.y * 64;
  int tid = threadIdx.x;
  int lane = tid & 63;
  int wid = __builtin_amdgcn_readfirstlane(tid >> 6);
  int wm = wid >> 1, wn = wid & 1;          // wave grid 4x2
  int p = lane >> 4;                        // quarter-wave
  int q = lane & 7;                         // 16B chunk within row
  int lr = lane >> 3;                       // row within 8-row stage group
  f32x4 acc[2][2] = {};
  for (int k0 = 0; k0 < K; k0 += 64) {
    {
      int rl0 = wid * 16 + lr;
      int gm0 = m0 + rl0; if (gm0 > M - 1) gm0 = M - 1;
      GLL16(A + (size_t)gm0 * K + k0 + ((q ^ (rl0 & 7)) << 3), &As[(wid * 16) * 64]);
      int rl1 = rl0 + 8;
      int gm1 = m0 + rl1; if (gm1 > M - 1) gm1 = M - 1;
      GLL16(A + (size_t)gm1 * K + k0 + ((q ^ (rl1 & 7)) << 3), &As[(wid * 16 + 8) * 64]);
      int rb = wid * 8 + lr;
      GLL16(WT + (size_t)(n0 + rb) * K + k0 + ((q ^ (rb & 7)) << 3), &Bs[(wid * 8) * 64]);
    }
    __syncthreads();
    #pragma unroll
    for (int kk = 0; kk < 64; kk += 32) {
      int cq = (kk >> 3) + p;
      int ra0 = wm * 32 + (lane & 15);
      int ra1 = ra0 + 16;
      int rb0 = wn * 32 + (lane & 15);
      int rb1 = rb0 + 16;
      bf16x8 a0 = *(const bf16x8*)&As[ra0 * 64 + ((cq ^ (ra0 & 7)) << 3)];
      bf16x8 a1 = *(const bf16x8*)&As[ra1 * 64 + ((cq ^ (ra1 & 7)) << 3)];
      bf16x8 b0 = *(const bf16x8*)&Bs[rb0 * 64 + ((cq ^ (rb0 & 7)) << 3)];
      bf16x8 b1 = *(const bf16x8*)&Bs[rb1 * 64 + ((cq ^ (rb1 & 7)) << 3)];
      acc[0][0] = __builtin_amdgcn_mfma_f32_16x16x32_bf16(a0, b0, acc[0][0], 0, 0, 0);
      acc[0][1] = __builtin_amdgcn_mfma_f32_16x16x32_bf16(a0, b1, acc[0][1], 0, 0, 0);
      acc[1][0] = __builtin_amdgcn_mfma_f32_16x16x32_bf16(a1, b0, acc[1][0], 0, 0, 0);
      acc[1][1] = __builtin_amdgcn_mfma_f32_16x16x32_bf16(a1, b1, acc[1][1], 0, 0, 0);
    }
    __syncthreads();
  }
  #pragma unroll
  for (int mi = 0; mi < 2; ++mi)
  #pragma unroll
  for (int ni = 0; ni < 2; ++ni)
  #pragma unroll
  for (int j = 0; j < 4; ++j) {
    int m = m0 + wm * 32 + mi * 16 + p * 4 + j;
    int c = n0 + wn * 32 + ni * 16 + (lane & 15);
    if (m >= M) continue;
    float v = acc[mi][ni][j];
    if (EPI == EPI_NONE) {
      outf[(size_t)m * 256 + c] = v;
    } else if (EPI == EPI_FZ) {
      float z = sigmoidf_(v + bfz[c]);
      float fw = b2f(A[(size_t)m * K + c]);
      float bw = b2f(A[(size_t)m * K + 256 + c]);
      Xzr[(size_t)m * 512 + 256 + c] = f2b((1.f - z) * fw + z * bw);
    } else if (EPI == EPI_ZR) {
      float s = sigmoidf_(v);
      if (c < 256) {
        zbuf[(size_t)m * 256 + c] = f2b(s);
        Xt[(size_t)m * 512 + 256 + c] = A[(size_t)m * 512 + 256 + c];  // copy bf16(agg)
      } else {
        int cz = c - 256;
        Xt[(size_t)m * 512 + cz] = f2b(s * ns[(size_t)m * 256 + cz]);  // r*h
      }
    } else { // EPI_GRU
      float t = tanhf(v);
      float zz = b2f(zbuf[(size_t)m * 256 + c]);
      float h = ns[(size_t)m * 256 + c];
      ns[(size_t)m * 256 + c] = (1.f - zz) * h + zz * t;
    }
  }
}

// ---------- output ----------
__global__ void transpose_out_kernel(const float4* __restrict__ ns4, float4* __restrict__ out4,
                                     ushort4* __restrict__ nsb4) {
  int w = __builtin_amdgcn_readfirstlane((int)(threadIdx.x >> 6));
  int bn = blockIdx.x * 4 + w;
  int lane = threadIdx.x & 63;
  int b = bn / Nn, n = bn % Nn;
  float4 v = ns4[(size_t)bn * 64 + lane];
  out4[((size_t)n * Bb + b) * 64 + lane] = v;
  nsb4[(size_t)bn * 64 + lane] = pack4(v);
}

__global__ void maxpart_kernel(const float* __restrict__ tmp, float* __restrict__ part) {
  int bc = blockIdx.x;             // b*12 + chunk (125 rows each)
  int b = bc / 12, ch = bc % 12;
  int h = threadIdx.x;
  float m = -1e30f;
  int nbase = ch * 125;
  for (int i = 0; i < 125; ++i)
    m = fmaxf(m, tmp[((size_t)b * Nn + nbase + i) * Hh + h]);
  part[(size_t)bc * Hh + h] = m;
}
__global__ void maxfin_kernel(const float* __restrict__ part, float* __restrict__ out) {
  int t = blockIdx.x * 256 + threadIdx.x;   // b*256 + h
  if (t >= Bb * Hh) return;
  int b = t / Hh, h = t % Hh;
  float m = -1e30f;
  for (int c = 0; c < 12; ++c) m = fmaxf(m, part[((size_t)b * 12 + c) * Hh + h]);
  out[(size_t)Nn * Bb * Hh + t] = m;
}

extern "C" void kernel_launch(void* const* d_in, const int* in_sizes, int n_in,
                              void* d_out, int out_size, void* d_ws, size_t ws_size,
                              hipStream_t stream) {
  const float* in_ns   = (const float*)d_in[0];
  const float* in_ev   = (const float*)d_in[1];
  const float* in_n2e  = (const float*)d_in[2];   // (B,E,N)
  const float* in_e2n  = (const float*)d_in[3];   // (B,N,E)
  const float* in_wmax = (const float*)d_in[4];
  const float* in_wfz  = (const float*)d_in[5];
  const float* in_bfz  = (const float*)d_in[6];
  const float* in_wz   = (const float*)d_in[7];
  const float* in_wr   = (const float*)d_in[8];
  const float* in_wt   = (const float*)d_in[9];
  float* out = (float*)d_out;

  char* base = (char*)d_ws;
  size_t off = 0;
  auto alloc = [&](size_t bytes) -> void* {
    void* r = base + off;
    off = (off + bytes + 255) & ~(size_t)255;
    return r;
  };
  // cntC (96000 B, 256-aligned) immediately followed by cntD -> single memset
  int* cntC = (int*)alloc(BE * 4);
  int* cntD = (int*)alloc(BN * 4);
  int* cntA = (int*)alloc(BE * 4);
  int* Aidx = (int*)alloc((size_t)BE * CAP * 4);
  int* cntB = (int*)alloc(BN * 4);
  int* Bidx = (int*)alloc((size_t)BN * CAP * 4);
  int* Cidx = (int*)alloc((size_t)BE * CAP * 4);
  int* Didx = (int*)alloc((size_t)BN * CAP * 4);
  float* ns   = (float*)alloc((size_t)Mrows * Hh * 4);
  unsigned short* evb = (unsigned short*)alloc((size_t)BE * Hh * 2); // bf16
  unsigned short* eb = (unsigned short*)alloc((size_t)BE * Hh * 2);  // bf16
  unsigned short* ef = (unsigned short*)alloc((size_t)BE * Hh * 2);  // bf16
  float* gout = (float*)alloc((size_t)Mrows * 256 * 4);
  unsigned short* Xfz = (unsigned short*)alloc((size_t)Mrows * 768 * 2);
  unsigned short* Xzr = (unsigned short*)alloc((size_t)Mrows * 512 * 2);
  unsigned short* Xt  = (unsigned short*)alloc((size_t)Mrows * 512 * 2);
  unsigned short* zbuf = (unsigned short*)alloc((size_t)Mrows * 256 * 2); // bf16
  unsigned short* nsb = (unsigned short*)alloc((size_t)Mrows * 256 * 2);
  float* part = (float*)alloc((size_t)Bb * 12 * Hh * 4);
  unsigned short* WfzT  = (unsigned short*)alloc(256 * 768 * 2);
  unsigned short* WzrT  = (unsigned short*)alloc(512 * 512 * 2);
  unsigned short* WtT   = (unsigned short*)alloc(256 * 512 * 2);
  unsigned short* WmaxT = (unsigned short*)alloc(256 * 256 * 2);
  (void)ws_size; (void)in_sizes; (void)n_in; (void)out_size;

  hipMemsetAsync(cntC, 0, (BE + BN) * 4, stream);

  preprocess_kernel<<<16060, 256, 0, stream>>>(
      in_n2e, in_e2n,
      Aidx, cntA, Didx, cntD, Bidx, cntB, Cidx, cntC,
      in_wfz, in_wz, in_wr, in_wt, in_wmax,
      WfzT, WzrT, WtT, WmaxT,
      in_ns, ns, in_ev, evb);
  sort2_kernel<<<(BE + BN + 255) / 256, 256, 0, stream>>>(Cidx, cntC, Didx, cntD);

  dim3 gFZ(94, 4), gZR(94, 8), gT(94, 4);
  for (int hop = 0; hop < NHOPS; ++hop) {
    edge_kernel<<<BE / 4, 256, 0, stream>>>((const ushort4*)evb, (const float4*)ns,
        Aidx, cntA, Cidx, cntC, (ushort4*)eb, (ushort4*)ef);
    node_kernel<<<BN / 4, 256, 0, stream>>>((const float4*)ns,
        (const ushort4*)eb, (const ushort4*)ef,
        Bidx, cntB, Didx, cntD, (ushort4*)Xfz, (ushort4*)Xzr);
    gemm_kernel<EPI_FZ><<<gFZ, 512, 0, stream>>>(Xfz, WfzT, Mrows, 768,
        nullptr, in_bfz, Xzr, nullptr, nullptr, nullptr);
    gemm_kernel<EPI_ZR><<<gZR, 512, 0, stream>>>(Xzr, WzrT, Mrows, 512,
        nullptr, nullptr, nullptr, zbuf, Xt, ns);
    gemm_kernel<EPI_GRU><<<gT, 512, 0, stream>>>(Xt, WtT, Mrows, 512,
        nullptr, nullptr, nullptr, zbuf, nullptr, ns);
  }

  transpose_out_kernel<<<BN / 4, 256, 0, stream>>>((const float4*)ns, (float4*)out,
                                                   (ushort4*)nsb);
  gemm_kernel<EPI_NONE><<<gT, 512, 0, stream>>>(nsb, WmaxT, Mrows, 256,
      gout, nullptr, nullptr, nullptr, nullptr, nullptr);
  maxpart_kernel<<<Bb * 12, 256, 0, stream>>>(gout, part);
  maxfin_kernel<<<(Bb * Hh + 255) / 256, 256, 0, stream>>>(part, out);
}

// Round 5
// 420.404 us; speedup vs baseline: 1.6479x; 1.0406x over previous
//
#include <hip/hip_runtime.h>
#include <hip/hip_bf16.h>
#include <stdint.h>

#define Bb 8
#define Nn 1500
#define Ee 3000
#define Hh 256
#define NHOPS 3
#define CAP 32
#define Mrows (Bb*Nn)      // 12000
#define BE (Bb*Ee)         // 24000
#define BN (Bb*Nn)         // 12000

typedef __bf16 bf16x8 __attribute__((ext_vector_type(8)));
typedef float f32x4 __attribute__((ext_vector_type(4)));

__device__ __forceinline__ float sigmoidf_(float x){ return 1.f/(1.f+__expf(-x)); }

__device__ __forceinline__ unsigned short f2b(float f){
  union { float f; unsigned int u; } x; x.f = f;
  unsigned int r = (x.u + 0x7fffu + ((x.u >> 16) & 1u)) >> 16;
  return (unsigned short)r;
}
__device__ __forceinline__ float b2f(unsigned short u){
  union { unsigned int u; float f; } x; x.u = ((unsigned int)u) << 16;
  return x.f;
}
__device__ __forceinline__ ushort4 pack4(float4 v){
  return make_ushort4(f2b(v.x), f2b(v.y), f2b(v.z), f2b(v.w));
}
__device__ __forceinline__ float4 unpack4(ushort4 u){
  return make_float4(b2f(u.x), b2f(u.y), b2f(u.z), b2f(u.w));
}

// async global->LDS, 16B per lane; LDS dest = uniform base + lane*16
#define GLL16(g, l) __builtin_amdgcn_global_load_lds( \
    (const __attribute__((address_space(1))) unsigned int*)(g), \
    (__attribute__((address_space(3))) unsigned int*)(l), 16, 0, 0)

// ---------- preprocess megakernel ----------
// sections (256 threads/block):
//  [0,6000)        rowscan n2e (4 rows/block, R=Ee, C=Nn, NQ=6)
//  [6000,9000)     rowscan e2n (R=Nn, C=Ee, NQ=12)
//  [9000,11560)    weight prep (655360 elems)
//  [11560,12310)   in_ns f32 -> nsb bf16 (4 float4/thread)
//  [12310,13810)   edge_vec f32 -> bf16 (4 float4/thread)
template<int NQ>
__device__ __forceinline__ void rowscan_body(const float* __restrict__ mat, int R, int C,
                                             int* __restrict__ rowIdx, int* __restrict__ rowCnt,
                                             int* __restrict__ colIdx, int* __restrict__ colCnt,
                                             int blk) {
  int w = __builtin_amdgcn_readfirstlane((int)(threadIdx.x >> 6));
  int g = blk * 4 + w;
  if (g >= Bb * R) return;
  int b = g / R;
  int lane = threadIdx.x & 63;
  const float4* base = (const float4*)(mat + (size_t)g * C);
  int nq = C >> 2;
  float4 v[NQ];
  #pragma unroll
  for (int i = 0; i < NQ; ++i) {
    int q = i * 64 + lane;
    v[i] = make_float4(0.f, 0.f, 0.f, 0.f);
    if (q < nq) v[i] = base[q];
  }
  int cnt = 0;
  #pragma unroll
  for (int i = 0; i < NQ; ++i) {
    unsigned long long m0 = __ballot(v[i].x != 0.f);
    unsigned long long m1 = __ballot(v[i].y != 0.f);
    unsigned long long m2 = __ballot(v[i].z != 0.f);
    unsigned long long m3 = __ballot(v[i].w != 0.f);
    unsigned long long below = (1ull << lane) - 1ull;
    int myc = cnt + __popcll(m0 & below) + __popcll(m1 & below)
                  + __popcll(m2 & below) + __popcll(m3 & below);
    int c = (i * 64 + lane) * 4;
    #pragma unroll
    for (int j = 0; j < 4; ++j) {
      float vv = (j == 0) ? v[i].x : (j == 1) ? v[i].y : (j == 2) ? v[i].z : v[i].w;
      if (vv != 0.f) {
        if (myc < CAP) rowIdx[(size_t)g * CAP + myc] = c + j;
        int slot = atomicAdd(&colCnt[b * C + c + j], 1);
        if (slot < CAP) colIdx[(size_t)(b * C + c + j) * CAP + slot] = g - b * R;
        ++myc;
      }
    }
    cnt += __popcll(m0) + __popcll(m1) + __popcll(m2) + __popcll(m3);
  }
  if (lane == 0) rowCnt[g] = cnt;
}

__global__ void preprocess_kernel(const float* __restrict__ n2e, const float* __restrict__ e2n,
                                  int* __restrict__ Aidx, int* __restrict__ cntA,
                                  int* __restrict__ Didx, int* __restrict__ cntD,
                                  int* __restrict__ Bidx, int* __restrict__ cntB,
                                  int* __restrict__ Cidx, int* __restrict__ cntC,
                                  const float* __restrict__ Wfz, const float* __restrict__ Wz,
                                  const float* __restrict__ Wr, const float* __restrict__ Wt,
                                  const float* __restrict__ Wmax,
                                  unsigned short* __restrict__ WfzT, unsigned short* __restrict__ WzrT,
                                  unsigned short* __restrict__ WtT, unsigned short* __restrict__ WmaxT,
                                  const float* __restrict__ in_ns, unsigned short* __restrict__ nsb,
                                  const float* __restrict__ in_ev, unsigned short* __restrict__ evb) {
  int bx = blockIdx.x;
  if (bx < 6000) {
    rowscan_body<6>(n2e, Ee, Nn, Aidx, cntA, Didx, cntD, bx);
  } else if (bx < 9000) {
    rowscan_body<12>(e2n, Nn, Ee, Bidx, cntB, Cidx, cntC, bx - 6000);
  } else if (bx < 11560) {
    int t = (bx - 9000) * 256 + threadIdx.x;
    if (t < 196608) {                       // WfzT': 256 n x 768 k (combined)
      int n = t / 768, k = t % 768;
      float v;
      if (k < 256)      v = Wfz[k * 256 + n] + Wfz[(k + 768) * 256 + n];
      else if (k < 512) v = Wfz[k * 256 + n] - Wfz[(k + 512) * 256 + n];
      else              v = Wfz[k * 256 + n];
      WfzT[t] = f2b(v);
    } else if (t < 458752) {                // WzrT: 512 j x 512 k
      int u = t - 196608;
      int j = u >> 9, k = u & 511;
      float v = (j < 256) ? Wz[k * 256 + j] : Wr[k * 256 + (j - 256)];
      WzrT[u] = f2b(v);
    } else if (t < 589824) {                // WtT: 256 n x 512 k
      int u = t - 458752;
      int n = u >> 9, k = u & 511;
      WtT[u] = f2b(Wt[k * 256 + n]);
    } else if (t < 655360) {                // WmaxT: 256 x 256
      int u = t - 589824;
      int n = u >> 8, k = u & 255;
      WmaxT[u] = f2b(Wmax[k * 256 + n]);
    }
  } else if (bx < 12310) {
    int t0 = (bx - 11560) * 1024 + threadIdx.x;   // 768000 float4
    #pragma unroll
    for (int r = 0; r < 4; ++r) {
      int t = t0 + r * 256;
      ((ushort4*)nsb)[t] = pack4(((const float4*)in_ns)[t]);
    }
  } else {
    int t0 = (bx - 12310) * 1024 + threadIdx.x;   // 1536000 float4
    #pragma unroll
    for (int r = 0; r < 4; ++r) {
      int t = t0 + r * 256;
      ((ushort4*)evb)[t] = pack4(((const float4*)in_ev)[t]);
    }
  }
}

__device__ __forceinline__ void sort_one(int* pp, int c) {
  if (c > CAP) c = CAP;
  int v[CAP];
  for (int j = 0; j < c; ++j) v[j] = pp[j];
  for (int j = 1; j < c; ++j) { int key = v[j]; int k = j - 1;
    while (k >= 0 && v[k] > key) { v[k+1] = v[k]; --k; } v[k+1] = key; }
  for (int j = 0; j < c; ++j) pp[j] = v[j];
}
__global__ void sort2_kernel(int* __restrict__ Cidx, const int* __restrict__ cntC,
                             int* __restrict__ Didx, const int* __restrict__ cntD) {
  int i = blockIdx.x * 256 + threadIdx.x;
  if (i < BE) sort_one(Cidx + (size_t)i * CAP, cntC[i]);
  else if (i < BE + BN) { int k = i - BE; sort_one(Didx + (size_t)k * CAP, cntD[k]); }
}

// ---------- per-hop: edge embedding (both directions), bf16 gathers, 4 edges/block ----------
__global__ void edge_kernel(const ushort4* __restrict__ evb4, const ushort4* __restrict__ nsb4,
                            const int* __restrict__ Aidx, const int* __restrict__ Acnt,
                            const int* __restrict__ Cidx, const int* __restrict__ Ccnt,
                            ushort4* __restrict__ eb4, ushort4* __restrict__ ef4) {
  int w = __builtin_amdgcn_readfirstlane((int)(threadIdx.x >> 6));
  int be = blockIdx.x * 4 + w;
  int lane = threadIdx.x & 63;
  int b = be / Ee;
  int cA = min(Acnt[be], CAP), cC = min(Ccnt[be], CAP);
  const int* pA = Aidx + (size_t)be * CAP;
  const int* pC = Cidx + (size_t)be * CAP;
  float4 ev = unpack4(evb4[(size_t)be * 64 + lane]);
  float4 sA = ev, sC = ev;
  for (int i = 0; i < cA; ++i) {
    int n = pA[i];
    float4 t = unpack4(nsb4[((size_t)b * Nn + n) * 64 + lane]);
    sA.x += t.x; sA.y += t.y; sA.z += t.z; sA.w += t.w;
  }
  for (int i = 0; i < cC; ++i) {
    int n = pC[i];
    float4 t = unpack4(nsb4[((size_t)b * Nn + n) * 64 + lane]);
    sC.x += t.x; sC.y += t.y; sC.z += t.z; sC.w += t.w;
  }
  eb4[(size_t)be * 64 + lane] = pack4(sA);
  ef4[(size_t)be * 64 + lane] = pack4(sC);
}

// ---------- per-hop: node aggregation + build GEMM inputs ----------
__global__ void node_kernel(const float4* __restrict__ nsin4,
                            const ushort4* __restrict__ eb4, const ushort4* __restrict__ ef4,
                            const int* __restrict__ Bidx, const int* __restrict__ Bcnt,
                            const int* __restrict__ Didx, const int* __restrict__ Dcnt,
                            ushort4* __restrict__ Xfz4, ushort4* __restrict__ Xzr4) {
  int w = __builtin_amdgcn_readfirstlane((int)(threadIdx.x >> 6));
  int bn = blockIdx.x * 4 + w;
  int lane = threadIdx.x & 63;
  int b = bn / Nn;
  int rB = Bcnt[bn], rD = Dcnt[bn];
  int cB = min(rB, CAP), cD = min(rD, CAP);
  const int* pB = Bidx + (size_t)bn * CAP;
  const int* pD = Didx + (size_t)bn * CAP;
  float4 h0 = nsin4[(size_t)bn * 64 + lane];
  float4 sb = h0, sf = h0;
  for (int i = 0; i < cB; ++i) {
    int e = pB[i];
    float4 t = unpack4(eb4[((size_t)b * Ee + e) * 64 + lane]);
    sb.x += t.x; sb.y += t.y; sb.z += t.z; sb.w += t.w;
  }
  for (int i = 0; i < cD; ++i) {
    int e = pD[i];
    float4 t = unpack4(ef4[((size_t)b * Ee + e) * 64 + lane]);
    sf.x += t.x; sf.y += t.y; sf.z += t.z; sf.w += t.w;
  }
  float ib = 1.f / (1.f + (float)rB), idf = 1.f / (1.f + (float)rD);
  sb.x *= ib; sb.y *= ib; sb.z *= ib; sb.w *= ib;
  sf.x *= idf; sf.y *= idf; sf.z *= idf; sf.w *= idf;
  float4 prod = make_float4(sf.x*sb.x, sf.y*sb.y, sf.z*sb.z, sf.w*sb.w);
  size_t m = bn;
  Xfz4[m * 192 +   0 + lane] = pack4(sf);
  Xfz4[m * 192 +  64 + lane] = pack4(sb);
  Xfz4[m * 192 + 128 + lane] = pack4(prod);
  Xzr4[m * 128 + lane] = pack4(h0);
}

// ---------- bf16 MFMA GEMM (global_load_lds + XOR chunk swizzle) ----------
#define EPI_NONE 0
#define EPI_FZ   1
#define EPI_ZR   2
#define EPI_GRU  3

template<int EPI, int LAST>
__global__ __launch_bounds__(512) void gemm_kernel(
    const unsigned short* __restrict__ A, const unsigned short* __restrict__ WT,
    int M, int K,
    float* __restrict__ outf, const float* __restrict__ bfz,
    unsigned short* __restrict__ Xzr, unsigned short* __restrict__ zbuf,
    unsigned short* __restrict__ Xt,
    const float* __restrict__ nsin, float* __restrict__ nsout,
    unsigned short* __restrict__ nsbout)
{
  __shared__ unsigned short As[128 * 64];
  __shared__ unsigned short Bs[64 * 64];
  int m0 = blockIdx.x * 128, n0 = blockIdx.y * 64;
  int tid = threadIdx.x;
  int lane = tid & 63;
  int wid = __builtin_amdgcn_readfirstlane(tid >> 6);
  int wm = wid >> 1, wn = wid & 1;          // wave grid 4x2
  int p = lane >> 4;                        // quarter-wave
  int q = lane & 7;                         // 16B chunk within row
  int lr = lane >> 3;                       // row within 8-row stage group
  f32x4 acc[2][2] = {};
  for (int k0 = 0; k0 < K; k0 += 64) {
    {
      int rl0 = wid * 16 + lr;
      int gm0 = m0 + rl0; if (gm0 > M - 1) gm0 = M - 1;
      GLL16(A + (size_t)gm0 * K + k0 + ((q ^ (rl0 & 7)) << 3), &As[(wid * 16) * 64]);
      int rl1 = rl0 + 8;
      int gm1 = m0 + rl1; if (gm1 > M - 1) gm1 = M - 1;
      GLL16(A + (size_t)gm1 * K + k0 + ((q ^ (rl1 & 7)) << 3), &As[(wid * 16 + 8) * 64]);
      int rb = wid * 8 + lr;
      GLL16(WT + (size_t)(n0 + rb) * K + k0 + ((q ^ (rb & 7)) << 3), &Bs[(wid * 8) * 64]);
    }
    __syncthreads();
    #pragma unroll
    for (int kk = 0; kk < 64; kk += 32) {
      int cq = (kk >> 3) + p;
      int ra0 = wm * 32 + (lane & 15);
      int ra1 = ra0 + 16;
      int rb0 = wn * 32 + (lane & 15);
      int rb1 = rb0 + 16;
      bf16x8 a0 = *(const bf16x8*)&As[ra0 * 64 + ((cq ^ (ra0 & 7)) << 3)];
      bf16x8 a1 = *(const bf16x8*)&As[ra1 * 64 + ((cq ^ (ra1 & 7)) << 3)];
      bf16x8 b0 = *(const bf16x8*)&Bs[rb0 * 64 + ((cq ^ (rb0 & 7)) << 3)];
      bf16x8 b1 = *(const bf16x8*)&Bs[rb1 * 64 + ((cq ^ (rb1 & 7)) << 3)];
      acc[0][0] = __builtin_amdgcn_mfma_f32_16x16x32_bf16(a0, b0, acc[0][0], 0, 0, 0);
      acc[0][1] = __builtin_amdgcn_mfma_f32_16x16x32_bf16(a0, b1, acc[0][1], 0, 0, 0);
      acc[1][0] = __builtin_amdgcn_mfma_f32_16x16x32_bf16(a1, b0, acc[1][0], 0, 0, 0);
      acc[1][1] = __builtin_amdgcn_mfma_f32_16x16x32_bf16(a1, b1, acc[1][1], 0, 0, 0);
    }
    __syncthreads();
  }
  #pragma unroll
  for (int mi = 0; mi < 2; ++mi)
  #pragma unroll
  for (int ni = 0; ni < 2; ++ni)
  #pragma unroll
  for (int j = 0; j < 4; ++j) {
    int m = m0 + wm * 32 + mi * 16 + p * 4 + j;
    int c = n0 + wn * 32 + ni * 16 + (lane & 15);
    if (m >= M) continue;
    float v = acc[mi][ni][j];
    if (EPI == EPI_NONE) {
      outf[(size_t)m * 256 + c] = v;
    } else if (EPI == EPI_FZ) {
      float z = sigmoidf_(v + bfz[c]);
      float fw = b2f(A[(size_t)m * K + c]);
      float bw = b2f(A[(size_t)m * K + 256 + c]);
      Xzr[(size_t)m * 512 + 256 + c] = f2b((1.f - z) * fw + z * bw);
    } else if (EPI == EPI_ZR) {
      float s = sigmoidf_(v);
      if (c < 256) {
        zbuf[(size_t)m * 256 + c] = f2b(s);
        Xt[(size_t)m * 512 + 256 + c] = A[(size_t)m * 512 + 256 + c];  // copy bf16(agg)
      } else {
        int cz = c - 256;
        Xt[(size_t)m * 512 + cz] = f2b(s * nsin[(size_t)m * 256 + cz]);  // r*h
      }
    } else { // EPI_GRU
      float t = tanhf(v);
      float zz = b2f(zbuf[(size_t)m * 256 + c]);
      float h = nsin[(size_t)m * 256 + c];
      float nh = (1.f - zz) * h + zz * t;
      nsbout[(size_t)m * 256 + c] = f2b(nh);
      if (LAST) {
        int bb = m / Nn, n = m - bb * Nn;
        nsout[((size_t)n * Bb + bb) * 256 + c] = nh;   // (N,B,H) output
      } else {
        nsout[(size_t)m * 256 + c] = nh;
      }
    }
  }
}

// ---------- output max pool ----------
__global__ void maxpart_kernel(const float* __restrict__ tmp, float* __restrict__ part) {
  int bc = blockIdx.x;             // b*12 + chunk (125 rows each)
  int b = bc / 12, ch = bc % 12;
  int h = threadIdx.x;
  float m = -1e30f;
  int nbase = ch * 125;
  for (int i = 0; i < 125; ++i)
    m = fmaxf(m, tmp[((size_t)b * Nn + nbase + i) * Hh + h]);
  part[(size_t)bc * Hh + h] = m;
}
__global__ void maxfin_kernel(const float* __restrict__ part, float* __restrict__ out) {
  int t = blockIdx.x * 256 + threadIdx.x;   // b*256 + h
  if (t >= Bb * Hh) return;
  int b = t / Hh, h = t % Hh;
  float m = -1e30f;
  for (int c = 0; c < 12; ++c) m = fmaxf(m, part[((size_t)b * 12 + c) * Hh + h]);
  out[(size_t)Nn * Bb * Hh + t] = m;
}

extern "C" void kernel_launch(void* const* d_in, const int* in_sizes, int n_in,
                              void* d_out, int out_size, void* d_ws, size_t ws_size,
                              hipStream_t stream) {
  const float* in_ns   = (const float*)d_in[0];
  const float* in_ev   = (const float*)d_in[1];
  const float* in_n2e  = (const float*)d_in[2];   // (B,E,N)
  const float* in_e2n  = (const float*)d_in[3];   // (B,N,E)
  const float* in_wmax = (const float*)d_in[4];
  const float* in_wfz  = (const float*)d_in[5];
  const float* in_bfz  = (const float*)d_in[6];
  const float* in_wz   = (const float*)d_in[7];
  const float* in_wr   = (const float*)d_in[8];
  const float* in_wt   = (const float*)d_in[9];
  float* out = (float*)d_out;

  char* base = (char*)d_ws;
  size_t off = 0;
  auto alloc = [&](size_t bytes) -> void* {
    void* r = base + off;
    off = (off + bytes + 255) & ~(size_t)255;
    return r;
  };
  // cntC immediately followed by cntD -> single memset
  int* cntC = (int*)alloc(BE * 4);
  int* cntD = (int*)alloc(BN * 4);
  int* cntA = (int*)alloc(BE * 4);
  int* Aidx = (int*)alloc((size_t)BE * CAP * 4);
  int* cntB = (int*)alloc(BN * 4);
  int* Bidx = (int*)alloc((size_t)BN * CAP * 4);
  int* Cidx = (int*)alloc((size_t)BE * CAP * 4);
  int* Didx = (int*)alloc((size_t)BN * CAP * 4);
  float* ns   = (float*)alloc((size_t)Mrows * Hh * 4);
  unsigned short* nsb = (unsigned short*)alloc((size_t)Mrows * Hh * 2); // bf16 node state
  unsigned short* evb = (unsigned short*)alloc((size_t)BE * Hh * 2); // bf16
  unsigned short* eb = (unsigned short*)alloc((size_t)BE * Hh * 2);  // bf16
  unsigned short* ef = (unsigned short*)alloc((size_t)BE * Hh * 2);  // bf16
  float* gout = (float*)alloc((size_t)Mrows * 256 * 4);
  unsigned short* Xfz = (unsigned short*)alloc((size_t)Mrows * 768 * 2);
  unsigned short* Xzr = (unsigned short*)alloc((size_t)Mrows * 512 * 2);
  unsigned short* Xt  = (unsigned short*)alloc((size_t)Mrows * 512 * 2);
  unsigned short* zbuf = (unsigned short*)alloc((size_t)Mrows * 256 * 2); // bf16
  float* part = (float*)alloc((size_t)Bb * 12 * Hh * 4);
  unsigned short* WfzT  = (unsigned short*)alloc(256 * 768 * 2);
  unsigned short* WzrT  = (unsigned short*)alloc(512 * 512 * 2);
  unsigned short* WtT   = (unsigned short*)alloc(256 * 512 * 2);
  unsigned short* WmaxT = (unsigned short*)alloc(256 * 256 * 2);
  (void)ws_size; (void)in_sizes; (void)n_in; (void)out_size;

  hipMemsetAsync(cntC, 0, (BE + BN) * 4, stream);

  preprocess_kernel<<<13810, 256, 0, stream>>>(
      in_n2e, in_e2n,
      Aidx, cntA, Didx, cntD, Bidx, cntB, Cidx, cntC,
      in_wfz, in_wz, in_wr, in_wt, in_wmax,
      WfzT, WzrT, WtT, WmaxT,
      in_ns, nsb, in_ev, evb);
  sort2_kernel<<<(BE + BN + 255) / 256, 256, 0, stream>>>(Cidx, cntC, Didx, cntD);

  dim3 gFZ(94, 4), gZR(94, 8), gT(94, 4);
  for (int hop = 0; hop < NHOPS; ++hop) {
    const float* nsin = (hop == 0) ? in_ns : ns;
    edge_kernel<<<BE / 4, 256, 0, stream>>>((const ushort4*)evb, (const ushort4*)nsb,
        Aidx, cntA, Cidx, cntC, (ushort4*)eb, (ushort4*)ef);
    node_kernel<<<BN / 4, 256, 0, stream>>>((const float4*)nsin,
        (const ushort4*)eb, (const ushort4*)ef,
        Bidx, cntB, Didx, cntD, (ushort4*)Xfz, (ushort4*)Xzr);
    gemm_kernel<EPI_FZ, 0><<<gFZ, 512, 0, stream>>>(Xfz, WfzT, Mrows, 768,
        nullptr, in_bfz, Xzr, nullptr, nullptr, nullptr, nullptr, nullptr);
    gemm_kernel<EPI_ZR, 0><<<gZR, 512, 0, stream>>>(Xzr, WzrT, Mrows, 512,
        nullptr, nullptr, nullptr, zbuf, Xt, nsin, nullptr, nullptr);
    if (hop < NHOPS - 1) {
      gemm_kernel<EPI_GRU, 0><<<gT, 512, 0, stream>>>(Xt, WtT, Mrows, 512,
          nullptr, nullptr, nullptr, zbuf, nullptr, nsin, ns, nsb);
    } else {
      gemm_kernel<EPI_GRU, 1><<<gT, 512, 0, stream>>>(Xt, WtT, Mrows, 512,
          nullptr, nullptr, nullptr, zbuf, nullptr, nsin, out, nsb);
    }
  }

  gemm_kernel<EPI_NONE, 0><<<gT, 512, 0, stream>>>(nsb, WmaxT, Mrows, 256,
      gout, nullptr, nullptr, nullptr, nullptr, nullptr, nullptr, nullptr);
  maxpart_kernel<<<Bb * 12, 256, 0, stream>>>(gout, part);
  maxfin_kernel<<<(Bb * Hh + 255) / 256, 256, 0, stream>>>(part, out);
}